// Round 1
// baseline (828.318 us; speedup 1.0000x reference)
//
#include <hip/hip_runtime.h>
#include <math.h>

#define N_NODES 50000
#define N_EDGES 600000
#define TOT (N_EDGES + N_NODES)   // 650000 edges incl. self-loops
#define HD 128
#define OUTW 384
#define NEG_SLOPE 0.2f

// ---------- helpers ----------

// order-preserving float->uint map for atomicMax-based segment max
static __device__ __forceinline__ unsigned f2o(float f){
  unsigned u = __float_as_uint(f);
  return (u & 0x80000000u) ? ~u : (u | 0x80000000u);
}
static __device__ __forceinline__ float o2f(unsigned o){
  unsigned u = (o & 0x80000000u) ? (o ^ 0x80000000u) : ~o;
  return __uint_as_float(u);
}

// edge_index may arrive as int32 or int64; runtime-detected flag (uniform branch)
static __device__ __forceinline__ int load_edge(const void* ei, int is64, long long off){
  return is64 ? (int)((const long long*)ei)[off] : ((const int*)ei)[off];
}

// ---------- one-time per-launch kernels ----------

__global__ void detect_idx_kernel(const void* ei, int* flag){
  // single thread: if first 64 values are valid node ids when read as int64 -> int64 layout
  const long long* p = (const long long*)ei;
  int ok = 1;
  for (int i = 0; i < 64; i++){
    long long v = p[i];
    if (v < 0 || v >= N_NODES){ ok = 0; break; }
  }
  *flag = ok;
}

__global__ __launch_bounds__(256) void mean_kernel(const float* __restrict__ ea, float* meansum){
  int tid = blockIdx.x * blockDim.x + threadIdx.x;
  float s = 0.f;
  for (int i = tid; i < N_EDGES; i += gridDim.x * blockDim.x) s += ea[i];
  for (int off = 32; off > 0; off >>= 1) s += __shfl_down(s, off, 64);
  __shared__ float ws[4];
  int lane = threadIdx.x & 63, w = threadIdx.x >> 6;
  if (lane == 0) ws[w] = s;
  __syncthreads();
  if (threadIdx.x == 0){
    atomicAdd(meansum, ws[0] + ws[1] + ws[2] + ws[3]);
  }
}

__global__ __launch_bounds__(128) void ce_kernel(const float* __restrict__ We0, const float* __restrict__ ae0,
                                                 const float* __restrict__ We1, const float* __restrict__ ae1,
                                                 float* scal){
  __shared__ float buf[128];
  int t = threadIdx.x;
  buf[t] = We0[t] * ae0[t];
  __syncthreads();
  for (int off = 64; off > 0; off >>= 1){ if (t < off) buf[t] += buf[t + off]; __syncthreads(); }
  if (t == 0) scal[1] = buf[0];
  __syncthreads();
  buf[t] = We1[t] * ae1[t];
  __syncthreads();
  for (int off = 64; off > 0; off >>= 1){ if (t < off) buf[t] += buf[t + off]; __syncthreads(); }
  if (t == 0) scal[2] = buf[0];
}

__global__ __launch_bounds__(256) void deg_kernel(const void* ei, const int* flag, int* deg){
  int e = blockIdx.x * 256 + threadIdx.x;
  if (e >= TOT) return;
  int is64 = *flag;
  int d = (e < N_EDGES) ? load_edge(ei, is64, (long long)N_EDGES + e) : (e - N_EDGES);
  atomicAdd(&deg[d], 1);
}

// exclusive scan of deg[0..N) -> rowstart, 1024-element chunks
__global__ __launch_bounds__(256) void scan_chunk_kernel(const int* __restrict__ deg,
                                                         int* __restrict__ rowstart,
                                                         int* __restrict__ chunksums){
  __shared__ int sums[256];
  int t = threadIdx.x;
  int base = blockIdx.x * 1024 + t * 4;
  int v[4];
  #pragma unroll
  for (int i = 0; i < 4; i++) v[i] = (base + i < N_NODES) ? deg[base + i] : 0;
  int tsum = v[0] + v[1] + v[2] + v[3];
  sums[t] = tsum;
  __syncthreads();
  for (int off = 1; off < 256; off <<= 1){
    int add = (t >= off) ? sums[t - off] : 0;
    __syncthreads();
    sums[t] += add;
    __syncthreads();
  }
  int run = sums[t] - tsum;   // exclusive prefix for this thread
  #pragma unroll
  for (int i = 0; i < 4; i++){
    if (base + i < N_NODES) rowstart[base + i] = run;
    run += v[i];
  }
  if (t == 255) chunksums[blockIdx.x] = sums[255];
}

__global__ void scan_top_kernel(int* chunksums, int nchunks){
  if (threadIdx.x == 0 && blockIdx.x == 0){
    int run = 0;
    for (int c = 0; c < nchunks; c++){ int v = chunksums[c]; chunksums[c] = run; run += v; }
  }
}

__global__ __launch_bounds__(256) void add_off_kernel(int* rowstart, const int* chunksums){
  int base = blockIdx.x * 1024 + threadIdx.x * 4;
  int off = chunksums[blockIdx.x];
  #pragma unroll
  for (int i = 0; i < 4; i++) if (base + i < N_NODES) rowstart[base + i] += off;
}

__global__ __launch_bounds__(256) void fill_kernel(const void* ei, const int* flag,
                                                   const int* __restrict__ rowstart, int* cursor,
                                                   int* __restrict__ csr_src, int* __restrict__ csr_eid){
  int e = blockIdx.x * 256 + threadIdx.x;
  if (e >= TOT) return;
  int is64 = *flag;
  int s, d;
  if (e < N_EDGES){
    s = load_edge(ei, is64, e);
    d = load_edge(ei, is64, (long long)N_EDGES + e);
  } else {
    s = d = e - N_EDGES;
  }
  int pos = rowstart[d] + atomicAdd(&cursor[d], 1);
  csr_src[pos] = s;
  csr_eid[pos] = e;
}

__global__ __launch_bounds__(256) void copyx_kernel(const float* __restrict__ x, float* __restrict__ out){
  int idx = blockIdx.x * 256 + threadIdx.x;
  if (idx >= N_NODES * HD) return;
  int n = idx >> 7, j = idx & 127;
  out[(size_t)n * OUTW + j] = x[idx];
}

// ---------- per-layer kernels ----------

// hp[r][j] = dot(hin[r,:], W[j,:]) ; W staged in LDS (stride 132 floats, 16B-aligned rows),
// h reads are wave-uniform -> scalar loads. 64 rows/block, 128 threads (thread = output col).
__global__ __launch_bounds__(128) void gemm_kernel(const float* __restrict__ hin,
                                                   const float* __restrict__ W,
                                                   float* __restrict__ hp){
  __shared__ float Wl[128 * 132];
  int t = threadIdx.x;
  const float4* W4 = (const float4*)W;
  for (int i = t; i < 4096; i += 128){
    float4 v = W4[i];
    int j = i >> 5;
    int k = (i & 31) << 2;
    *(float4*)&Wl[j * 132 + k] = v;
  }
  __syncthreads();
  int rb = blockIdx.x * 64;
  for (int rc = 0; rc < 64; rc += 8){
    int r0 = rb + rc;
    if (r0 >= N_NODES) return;          // N%8==0 so chunks are all-or-nothing
    float acc[8] = {0.f,0.f,0.f,0.f,0.f,0.f,0.f,0.f};
    const float* hrow = hin + (size_t)r0 * HD;
    for (int k = 0; k < 128; k += 4){
      float4 wv = *(const float4*)&Wl[t * 132 + k];
      #pragma unroll
      for (int rr = 0; rr < 8; rr++){
        float4 hv = *(const float4*)&hrow[rr * HD + k];
        acc[rr] = fmaf(hv.w, wv.w, fmaf(hv.z, wv.z, fmaf(hv.y, wv.y, fmaf(hv.x, wv.x, acc[rr]))));
      }
    }
    #pragma unroll
    for (int rr = 0; rr < 8; rr++) hp[(size_t)(r0 + rr) * HD + t] = acc[rr];
  }
}

// ssrc[n] = dot(hp[n], att_src), sdst[n] = dot(hp[n], att_dst); one wave per node
__global__ __launch_bounds__(256) void score_kernel(const float* __restrict__ hp,
                                                    const float* __restrict__ as_,
                                                    const float* __restrict__ ad_,
                                                    float* __restrict__ ssrc, float* __restrict__ sdst){
  int w = threadIdx.x >> 6, lane = threadIdx.x & 63;
  int n = blockIdx.x * 4 + w;
  if (n >= N_NODES) return;
  const float* row = hp + (size_t)n * HD;
  float a0 = row[lane], a1 = row[64 + lane];
  float ps = a0 * as_[lane] + a1 * as_[64 + lane];
  float pd = a0 * ad_[lane] + a1 * ad_[64 + lane];
  for (int off = 32; off > 0; off >>= 1){
    ps += __shfl_down(ps, off, 64);
    pd += __shfl_down(pd, off, 64);
  }
  if (lane == 0){ ssrc[n] = ps; sdst[n] = pd; }
}

__global__ __launch_bounds__(256) void alpha_kernel(const void* ei, const int* flag,
                                                    const float* __restrict__ eattr,
                                                    const float* __restrict__ ssrc,
                                                    const float* __restrict__ sdst,
                                                    const float* __restrict__ scal, int which,
                                                    float* __restrict__ alpha, unsigned* maxbuf){
  int e = blockIdx.x * 256 + threadIdx.x;
  if (e >= TOT) return;
  int is64 = *flag;
  int s, d; float eav;
  if (e < N_EDGES){
    s = load_edge(ei, is64, e);
    d = load_edge(ei, is64, (long long)N_EDGES + e);
    eav = eattr[e];
  } else {
    s = d = e - N_EDGES;
    eav = scal[0] * (1.0f / (float)N_EDGES);   // mean fill
  }
  float a = ssrc[s] + sdst[d] + eav * scal[1 + which];
  a = (a >= 0.f) ? a : NEG_SLOPE * a;          // leaky_relu
  alpha[e] = a;
  atomicMax(&maxbuf[d], f2o(a));
}

__global__ __launch_bounds__(256) void exp_kernel(const void* ei, const int* flag,
                                                  const float* __restrict__ alpha,
                                                  const unsigned* __restrict__ maxbuf,
                                                  float* __restrict__ wexp, float* __restrict__ denom){
  int e = blockIdx.x * 256 + threadIdx.x;
  if (e >= TOT) return;
  int is64 = *flag;
  int d = (e < N_EDGES) ? load_edge(ei, is64, (long long)N_EDGES + e) : (e - N_EDGES);
  float m = o2f(maxbuf[d]);
  float w = expf(alpha[e] - m);
  wexp[e] = w;
  atomicAdd(&denom[d], w);
}

// one block per dst node: atomic-free weighted aggregation over its CSR row
__global__ __launch_bounds__(128) void agg_kernel(const int* __restrict__ rowstart,
                                                  const int* __restrict__ csr_src,
                                                  const int* __restrict__ csr_eid,
                                                  const float* __restrict__ wexp,
                                                  const float* __restrict__ denom,
                                                  const float* __restrict__ hp,
                                                  const float* __restrict__ bias,
                                                  float* __restrict__ hnext,
                                                  float* __restrict__ out, int outoff){
  int n = blockIdx.x;
  int j = threadIdx.x;
  int s0 = rowstart[n];
  int s1 = (n + 1 < N_NODES) ? rowstart[n + 1] : TOT;
  float inv = 1.0f / (denom[n] + 1e-16f);
  float acc = 0.f;
  for (int i = s0; i < s1; i++){
    int sn = csr_src[i];
    int e  = csr_eid[i];
    float p = wexp[e] * inv;
    acc = fmaf(p, hp[(size_t)sn * HD + j], acc);
  }
  float v = acc + bias[j];
  v = v > 0.f ? v : 0.f;                       // outer relu
  if (hnext) hnext[(size_t)n * HD + j] = v;
  out[(size_t)n * OUTW + outoff + j] = v;
}

// ---------- launch ----------

extern "C" void kernel_launch(void* const* d_in, const int* in_sizes, int n_in,
                              void* d_out, int out_size, void* d_ws, size_t ws_size,
                              hipStream_t stream){
  (void)in_sizes; (void)n_in; (void)out_size; (void)ws_size;
  const float* x    = (const float*)d_in[0];
  const void*  ei   = d_in[1];
  const float* eatt = (const float*)d_in[2];
  const float* W0   = (const float*)d_in[3];
  const float* as0  = (const float*)d_in[4];
  const float* ad0  = (const float*)d_in[5];
  const float* We0  = (const float*)d_in[6];
  const float* ae0  = (const float*)d_in[7];
  const float* b0   = (const float*)d_in[8];
  const float* W1   = (const float*)d_in[9];
  const float* as1  = (const float*)d_in[10];
  const float* ad1  = (const float*)d_in[11];
  const float* We1  = (const float*)d_in[12];
  const float* ae1  = (const float*)d_in[13];
  const float* b1   = (const float*)d_in[14];
  float* out = (float*)d_out;

  char* ws = (char*)d_ws;
  size_t off = 0;
  auto alloc = [&](size_t bytes) -> void* {
    void* p = ws + off;
    off += (bytes + 255) & ~(size_t)255;
    return p;
  };
  float*    hp       = (float*)   alloc((size_t)N_NODES * HD * 4);
  float*    h1       = (float*)   alloc((size_t)N_NODES * HD * 4);
  float*    ssrc     = (float*)   alloc((size_t)N_NODES * 4);
  float*    sdst     = (float*)   alloc((size_t)N_NODES * 4);
  float*    alpha    = (float*)   alloc((size_t)TOT * 4);
  float*    wexp     = (float*)   alloc((size_t)TOT * 4);
  unsigned* maxbuf   = (unsigned*)alloc((size_t)N_NODES * 4);
  float*    denom    = (float*)   alloc((size_t)N_NODES * 4);
  int*      deg      = (int*)     alloc((size_t)N_NODES * 4);
  int*      rowstart = (int*)     alloc((size_t)N_NODES * 4);
  int*      cursor   = (int*)     alloc((size_t)N_NODES * 4);
  int*      csr_src  = (int*)     alloc((size_t)TOT * 4);
  int*      csr_eid  = (int*)     alloc((size_t)TOT * 4);
  int*      chunksums= (int*)     alloc(64 * 4);
  float*    scal     = (float*)   alloc(64 * 4);   // [0]=sum(edge_attr) [1]=ce0 [2]=ce1
  int*      flag     = (int*)     alloc(64);

  hipMemsetAsync(deg,    0, (size_t)N_NODES * 4, stream);
  hipMemsetAsync(cursor, 0, (size_t)N_NODES * 4, stream);
  hipMemsetAsync(maxbuf, 0, (size_t)N_NODES * 4, stream);
  hipMemsetAsync(denom,  0, (size_t)N_NODES * 4, stream);
  hipMemsetAsync(scal,   0, 64 * 4, stream);

  const int EB = (TOT + 255) / 256;
  const int nchunks = (N_NODES + 1023) / 1024;

  detect_idx_kernel<<<1, 1, 0, stream>>>(ei, flag);
  mean_kernel<<<256, 256, 0, stream>>>(eatt, scal);
  ce_kernel<<<1, 128, 0, stream>>>(We0, ae0, We1, ae1, scal);
  deg_kernel<<<EB, 256, 0, stream>>>(ei, flag, deg);
  scan_chunk_kernel<<<nchunks, 256, 0, stream>>>(deg, rowstart, chunksums);
  scan_top_kernel<<<1, 64, 0, stream>>>(chunksums, nchunks);
  add_off_kernel<<<nchunks, 256, 0, stream>>>(rowstart, chunksums);
  fill_kernel<<<EB, 256, 0, stream>>>(ei, flag, rowstart, cursor, csr_src, csr_eid);
  copyx_kernel<<<(N_NODES * HD + 255) / 256, 256, 0, stream>>>(x, out);

  const int GB = (N_NODES + 63) / 64;   // 782

  // layer 0
  gemm_kernel<<<GB, 128, 0, stream>>>(x, W0, hp);
  score_kernel<<<(N_NODES + 3) / 4, 256, 0, stream>>>(hp, as0, ad0, ssrc, sdst);
  alpha_kernel<<<EB, 256, 0, stream>>>(ei, flag, eatt, ssrc, sdst, scal, 0, alpha, maxbuf);
  exp_kernel<<<EB, 256, 0, stream>>>(ei, flag, alpha, maxbuf, wexp, denom);
  agg_kernel<<<N_NODES, 128, 0, stream>>>(rowstart, csr_src, csr_eid, wexp, denom, hp, b0, h1, out, 128);

  // layer 1
  hipMemsetAsync(maxbuf, 0, (size_t)N_NODES * 4, stream);
  hipMemsetAsync(denom,  0, (size_t)N_NODES * 4, stream);
  gemm_kernel<<<GB, 128, 0, stream>>>(h1, W1, hp);
  score_kernel<<<(N_NODES + 3) / 4, 256, 0, stream>>>(hp, as1, ad1, ssrc, sdst);
  alpha_kernel<<<EB, 256, 0, stream>>>(ei, flag, eatt, ssrc, sdst, scal, 1, alpha, maxbuf);
  exp_kernel<<<EB, 256, 0, stream>>>(ei, flag, alpha, maxbuf, wexp, denom);
  agg_kernel<<<N_NODES, 128, 0, stream>>>(rowstart, csr_src, csr_eid, wexp, denom, hp, b1, nullptr, out, 256);
}

// Round 2
// 615.712 us; speedup vs baseline: 1.3453x; 1.3453x over previous
//
#include <hip/hip_runtime.h>
#include <math.h>

#define N_NODES 50000
#define N_EDGES 600000
#define TOT (N_EDGES + N_NODES)   // 650000 edges incl. self-loops
#define HD 128
#define OUTW 384
#define NEG_SLOPE 0.2f

// ---------- helpers ----------

// order-preserving float->uint map for atomicMax-based segment max
static __device__ __forceinline__ unsigned f2o(float f){
  unsigned u = __float_as_uint(f);
  return (u & 0x80000000u) ? ~u : (u | 0x80000000u);
}
static __device__ __forceinline__ float o2f(unsigned o){
  unsigned u = (o & 0x80000000u) ? (o ^ 0x80000000u) : ~o;
  return __uint_as_float(u);
}

// edge_index may arrive as int32 or int64; runtime-detected flag (uniform branch)
static __device__ __forceinline__ int load_edge(const void* ei, int is64, long long off){
  return is64 ? (int)((const long long*)ei)[off] : ((const int*)ei)[off];
}

// ---------- one-time per-launch kernels ----------

__global__ void detect_idx_kernel(const void* ei, int* flag){
  const long long* p = (const long long*)ei;
  int ok = 1;
  for (int i = 0; i < 64; i++){
    long long v = p[i];
    if (v < 0 || v >= N_NODES){ ok = 0; break; }
  }
  *flag = ok;
}

__global__ __launch_bounds__(256) void mean_kernel(const float* __restrict__ ea, float* meansum){
  int tid = blockIdx.x * blockDim.x + threadIdx.x;
  float s = 0.f;
  for (int i = tid; i < N_EDGES; i += gridDim.x * blockDim.x) s += ea[i];
  for (int off = 32; off > 0; off >>= 1) s += __shfl_down(s, off, 64);
  __shared__ float ws[4];
  int lane = threadIdx.x & 63, w = threadIdx.x >> 6;
  if (lane == 0) ws[w] = s;
  __syncthreads();
  if (threadIdx.x == 0){
    atomicAdd(meansum, ws[0] + ws[1] + ws[2] + ws[3]);
  }
}

__global__ __launch_bounds__(128) void ce_kernel(const float* __restrict__ We0, const float* __restrict__ ae0,
                                                 const float* __restrict__ We1, const float* __restrict__ ae1,
                                                 float* scal){
  __shared__ float buf[128];
  int t = threadIdx.x;
  buf[t] = We0[t] * ae0[t];
  __syncthreads();
  for (int off = 64; off > 0; off >>= 1){ if (t < off) buf[t] += buf[t + off]; __syncthreads(); }
  if (t == 0) scal[1] = buf[0];
  __syncthreads();
  buf[t] = We1[t] * ae1[t];
  __syncthreads();
  for (int off = 64; off > 0; off >>= 1){ if (t < off) buf[t] += buf[t + off]; __syncthreads(); }
  if (t == 0) scal[2] = buf[0];
}

__global__ __launch_bounds__(256) void deg_kernel(const void* ei, const int* flag, int* deg){
  int e = blockIdx.x * 256 + threadIdx.x;
  if (e >= TOT) return;
  int is64 = *flag;
  int d = (e < N_EDGES) ? load_edge(ei, is64, (long long)N_EDGES + e) : (e - N_EDGES);
  atomicAdd(&deg[d], 1);
}

// exclusive scan of deg[0..N) -> rowstart, 1024-element chunks
__global__ __launch_bounds__(256) void scan_chunk_kernel(const int* __restrict__ deg,
                                                         int* __restrict__ rowstart,
                                                         int* __restrict__ chunksums){
  __shared__ int sums[256];
  int t = threadIdx.x;
  int base = blockIdx.x * 1024 + t * 4;
  int v[4];
  #pragma unroll
  for (int i = 0; i < 4; i++) v[i] = (base + i < N_NODES) ? deg[base + i] : 0;
  int tsum = v[0] + v[1] + v[2] + v[3];
  sums[t] = tsum;
  __syncthreads();
  for (int off = 1; off < 256; off <<= 1){
    int add = (t >= off) ? sums[t - off] : 0;
    __syncthreads();
    sums[t] += add;
    __syncthreads();
  }
  int run = sums[t] - tsum;
  #pragma unroll
  for (int i = 0; i < 4; i++){
    if (base + i < N_NODES) rowstart[base + i] = run;
    run += v[i];
  }
  if (t == 255) chunksums[blockIdx.x] = sums[255];
}

__global__ void scan_top_kernel(int* chunksums, int nchunks){
  if (threadIdx.x == 0 && blockIdx.x == 0){
    int run = 0;
    for (int c = 0; c < nchunks; c++){ int v = chunksums[c]; chunksums[c] = run; run += v; }
  }
}

__global__ __launch_bounds__(256) void add_off_kernel(int* rowstart, const int* chunksums){
  int base = blockIdx.x * 1024 + threadIdx.x * 4;
  int off = chunksums[blockIdx.x];
  #pragma unroll
  for (int i = 0; i < 4; i++) if (base + i < N_NODES) rowstart[base + i] += off;
}

__global__ __launch_bounds__(256) void fill_kernel(const void* ei, const int* flag,
                                                   const int* __restrict__ rowstart, int* cursor,
                                                   int* __restrict__ csr_src, int* __restrict__ csr_eid){
  int e = blockIdx.x * 256 + threadIdx.x;
  if (e >= TOT) return;
  int is64 = *flag;
  int s, d;
  if (e < N_EDGES){
    s = load_edge(ei, is64, e);
    d = load_edge(ei, is64, (long long)N_EDGES + e);
  } else {
    s = d = e - N_EDGES;
  }
  int pos = rowstart[d] + atomicAdd(&cursor[d], 1);
  csr_src[pos] = s;
  csr_eid[pos] = e;
}

__global__ __launch_bounds__(256) void copyx_kernel(const float* __restrict__ x, float* __restrict__ out){
  int idx = blockIdx.x * 256 + threadIdx.x;   // one float4 per thread
  if (idx >= N_NODES * HD / 4) return;
  int n = idx >> 5;            // 32 float4 per row
  int j4 = idx & 31;
  float4 v = ((const float4*)x)[idx];
  *(float4*)&out[(size_t)n * OUTW + j4 * 4] = v;
}

// ---------- per-layer kernels ----------

// Register-tiled fp32 GEMM: hp[M=50000, 128] = hin[M,128] @ W[128,128]^T
// BM=64 rows/block, BN=128 (all cols), BK=16, 128 threads, 8x8 per thread.
#define BM 64
#define BK 16

__global__ __launch_bounds__(128, 3) void gemm_kernel(const float* __restrict__ hin,
                                                      const float* __restrict__ W,
                                                      float* __restrict__ hp){
  __shared__ float As[BK][BM + 4];    // 16 x 68 floats = 4.25 KB
  __shared__ float Ws[BK][HD + 4];    // 16 x 132 floats = 8.25 KB
  int t  = threadIdx.x;
  int tx = t & 15;          // col group: cols tx*8 .. +7
  int ty = t >> 4;          // row group: rows ty*8 .. +7
  int rb = blockIdx.x * BM;

  float acc[8][8];
  #pragma unroll
  for (int i = 0; i < 8; i++)
    #pragma unroll
    for (int j = 0; j < 8; j++) acc[i][j] = 0.f;

  for (int kb = 0; kb < HD; kb += BK){
    // stage A chunk: 64 rows x 16 k, transposed into As[k][m]
    #pragma unroll
    for (int p = 0; p < 2; p++){
      int idx = t + p * 128;          // 0..255
      int row = idx >> 2;             // 0..63
      int kq  = (idx & 3) << 2;       // 0,4,8,12
      int gr  = rb + row;
      if (gr > N_NODES - 1) gr = N_NODES - 1;   // clamp (tail rows never stored)
      float4 v = *(const float4*)&hin[(size_t)gr * HD + kb + kq];
      As[kq + 0][row] = v.x; As[kq + 1][row] = v.y;
      As[kq + 2][row] = v.z; As[kq + 3][row] = v.w;
    }
    // stage W chunk: 128 cols x 16 k, transposed into Ws[k][n]
    #pragma unroll
    for (int p = 0; p < 4; p++){
      int idx = t + p * 128;          // 0..511
      int n   = idx >> 2;             // 0..127
      int kq  = (idx & 3) << 2;
      float4 v = *(const float4*)&W[(size_t)n * HD + kb + kq];
      Ws[kq + 0][n] = v.x; Ws[kq + 1][n] = v.y;
      Ws[kq + 2][n] = v.z; Ws[kq + 3][n] = v.w;
    }
    __syncthreads();
    #pragma unroll
    for (int k = 0; k < BK; k++){
      float a[8], w[8];
      *(float4*)&a[0] = *(const float4*)&As[k][ty * 8];
      *(float4*)&a[4] = *(const float4*)&As[k][ty * 8 + 4];
      *(float4*)&w[0] = *(const float4*)&Ws[k][tx * 8];
      *(float4*)&w[4] = *(const float4*)&Ws[k][tx * 8 + 4];
      #pragma unroll
      for (int i = 0; i < 8; i++)
        #pragma unroll
        for (int j = 0; j < 8; j++)
          acc[i][j] = fmaf(a[i], w[j], acc[i][j]);
    }
    __syncthreads();
  }

  #pragma unroll
  for (int i = 0; i < 8; i++){
    int r = rb + ty * 8 + i;
    if (r < N_NODES){
      float* dst = &hp[(size_t)r * HD + tx * 8];
      *(float4*)&dst[0] = make_float4(acc[i][0], acc[i][1], acc[i][2], acc[i][3]);
      *(float4*)&dst[4] = make_float4(acc[i][4], acc[i][5], acc[i][6], acc[i][7]);
    }
  }
}

// ssrc[n] = dot(hp[n], att_src), sdst[n] = dot(hp[n], att_dst); one wave per node
__global__ __launch_bounds__(256) void score_kernel(const float* __restrict__ hp,
                                                    const float* __restrict__ as_,
                                                    const float* __restrict__ ad_,
                                                    float* __restrict__ ssrc, float* __restrict__ sdst){
  int w = threadIdx.x >> 6, lane = threadIdx.x & 63;
  int n = blockIdx.x * 4 + w;
  if (n >= N_NODES) return;
  const float* row = hp + (size_t)n * HD;
  float a0 = row[lane], a1 = row[64 + lane];
  float ps = a0 * as_[lane] + a1 * as_[64 + lane];
  float pd = a0 * ad_[lane] + a1 * ad_[64 + lane];
  for (int off = 32; off > 0; off >>= 1){
    ps += __shfl_down(ps, off, 64);
    pd += __shfl_down(pd, off, 64);
  }
  if (lane == 0){ ssrc[n] = ps; sdst[n] = pd; }
}

__global__ __launch_bounds__(256) void alpha_kernel(const void* ei, const int* flag,
                                                    const float* __restrict__ eattr,
                                                    const float* __restrict__ ssrc,
                                                    const float* __restrict__ sdst,
                                                    const float* __restrict__ scal, int which,
                                                    float* __restrict__ alpha, unsigned* maxbuf){
  int e = blockIdx.x * 256 + threadIdx.x;
  if (e >= TOT) return;
  int is64 = *flag;
  int s, d; float eav;
  if (e < N_EDGES){
    s = load_edge(ei, is64, e);
    d = load_edge(ei, is64, (long long)N_EDGES + e);
    eav = eattr[e];
  } else {
    s = d = e - N_EDGES;
    eav = scal[0] * (1.0f / (float)N_EDGES);   // mean fill
  }
  float a = ssrc[s] + sdst[d] + eav * scal[1 + which];
  a = (a >= 0.f) ? a : NEG_SLOPE * a;          // leaky_relu
  alpha[e] = a;
  atomicMax(&maxbuf[d], f2o(a));
}

__global__ __launch_bounds__(256) void exp_kernel(const void* ei, const int* flag,
                                                  const float* __restrict__ alpha,
                                                  const unsigned* __restrict__ maxbuf,
                                                  float* __restrict__ wexp, float* __restrict__ denom){
  int e = blockIdx.x * 256 + threadIdx.x;
  if (e >= TOT) return;
  int is64 = *flag;
  int d = (e < N_EDGES) ? load_edge(ei, is64, (long long)N_EDGES + e) : (e - N_EDGES);
  float m = o2f(maxbuf[d]);
  float w = expf(alpha[e] - m);
  wexp[e] = w;
  atomicAdd(&denom[d], w);
}

// one block per dst node: atomic-free weighted aggregation over its CSR row
__global__ __launch_bounds__(128) void agg_kernel(const int* __restrict__ rowstart,
                                                  const int* __restrict__ csr_src,
                                                  const int* __restrict__ csr_eid,
                                                  const float* __restrict__ wexp,
                                                  const float* __restrict__ denom,
                                                  const float* __restrict__ hp,
                                                  const float* __restrict__ bias,
                                                  float* __restrict__ hnext,
                                                  float* __restrict__ out, int outoff){
  int n = blockIdx.x;
  int j = threadIdx.x;
  int s0 = rowstart[n];
  int s1 = (n + 1 < N_NODES) ? rowstart[n + 1] : TOT;
  float inv = 1.0f / (denom[n] + 1e-16f);
  float acc = 0.f;
  for (int i = s0; i < s1; i++){
    int sn = csr_src[i];
    int e  = csr_eid[i];
    float p = wexp[e] * inv;
    acc = fmaf(p, hp[(size_t)sn * HD + j], acc);
  }
  float v = acc + bias[j];
  v = v > 0.f ? v : 0.f;                       // outer relu
  if (hnext) hnext[(size_t)n * HD + j] = v;
  out[(size_t)n * OUTW + outoff + j] = v;
}

// ---------- launch ----------

extern "C" void kernel_launch(void* const* d_in, const int* in_sizes, int n_in,
                              void* d_out, int out_size, void* d_ws, size_t ws_size,
                              hipStream_t stream){
  (void)in_sizes; (void)n_in; (void)out_size; (void)ws_size;
  const float* x    = (const float*)d_in[0];
  const void*  ei   = d_in[1];
  const float* eatt = (const float*)d_in[2];
  const float* W0   = (const float*)d_in[3];
  const float* as0  = (const float*)d_in[4];
  const float* ad0  = (const float*)d_in[5];
  const float* We0  = (const float*)d_in[6];
  const float* ae0  = (const float*)d_in[7];
  const float* b0   = (const float*)d_in[8];
  const float* W1   = (const float*)d_in[9];
  const float* as1  = (const float*)d_in[10];
  const float* ad1  = (const float*)d_in[11];
  const float* We1  = (const float*)d_in[12];
  const float* ae1  = (const float*)d_in[13];
  const float* b1   = (const float*)d_in[14];
  float* out = (float*)d_out;

  char* ws = (char*)d_ws;
  size_t off = 0;
  auto alloc = [&](size_t bytes) -> void* {
    void* p = ws + off;
    off += (bytes + 255) & ~(size_t)255;
    return p;
  };
  float*    hp       = (float*)   alloc((size_t)N_NODES * HD * 4);
  float*    h1       = (float*)   alloc((size_t)N_NODES * HD * 4);
  float*    ssrc     = (float*)   alloc((size_t)N_NODES * 4);
  float*    sdst     = (float*)   alloc((size_t)N_NODES * 4);
  float*    alpha    = (float*)   alloc((size_t)TOT * 4);
  float*    wexp     = (float*)   alloc((size_t)TOT * 4);
  unsigned* maxbuf   = (unsigned*)alloc((size_t)N_NODES * 4);
  float*    denom    = (float*)   alloc((size_t)N_NODES * 4);
  int*      deg      = (int*)     alloc((size_t)N_NODES * 4);
  int*      rowstart = (int*)     alloc((size_t)N_NODES * 4);
  int*      cursor   = (int*)     alloc((size_t)N_NODES * 4);
  int*      csr_src  = (int*)     alloc((size_t)TOT * 4);
  int*      csr_eid  = (int*)     alloc((size_t)TOT * 4);
  int*      chunksums= (int*)     alloc(64 * 4);
  float*    scal     = (float*)   alloc(64 * 4);   // [0]=sum(edge_attr) [1]=ce0 [2]=ce1
  int*      flag     = (int*)     alloc(64);

  hipMemsetAsync(deg,    0, (size_t)N_NODES * 4, stream);
  hipMemsetAsync(cursor, 0, (size_t)N_NODES * 4, stream);
  hipMemsetAsync(maxbuf, 0, (size_t)N_NODES * 4, stream);
  hipMemsetAsync(denom,  0, (size_t)N_NODES * 4, stream);
  hipMemsetAsync(scal,   0, 64 * 4, stream);

  const int EB = (TOT + 255) / 256;
  const int nchunks = (N_NODES + 1023) / 1024;

  detect_idx_kernel<<<1, 1, 0, stream>>>(ei, flag);
  mean_kernel<<<256, 256, 0, stream>>>(eatt, scal);
  ce_kernel<<<1, 128, 0, stream>>>(We0, ae0, We1, ae1, scal);
  deg_kernel<<<EB, 256, 0, stream>>>(ei, flag, deg);
  scan_chunk_kernel<<<nchunks, 256, 0, stream>>>(deg, rowstart, chunksums);
  scan_top_kernel<<<1, 64, 0, stream>>>(chunksums, nchunks);
  add_off_kernel<<<nchunks, 256, 0, stream>>>(rowstart, chunksums);
  fill_kernel<<<EB, 256, 0, stream>>>(ei, flag, rowstart, cursor, csr_src, csr_eid);
  copyx_kernel<<<(N_NODES * HD / 4 + 255) / 256, 256, 0, stream>>>(x, out);

  const int GB = (N_NODES + BM - 1) / BM;   // 782

  // layer 0
  gemm_kernel<<<GB, 128, 0, stream>>>(x, W0, hp);
  score_kernel<<<(N_NODES + 3) / 4, 256, 0, stream>>>(hp, as0, ad0, ssrc, sdst);
  alpha_kernel<<<EB, 256, 0, stream>>>(ei, flag, eatt, ssrc, sdst, scal, 0, alpha, maxbuf);
  exp_kernel<<<EB, 256, 0, stream>>>(ei, flag, alpha, maxbuf, wexp, denom);
  agg_kernel<<<N_NODES, 128, 0, stream>>>(rowstart, csr_src, csr_eid, wexp, denom, hp, b0, h1, out, 128);

  // layer 1
  hipMemsetAsync(maxbuf, 0, (size_t)N_NODES * 4, stream);
  hipMemsetAsync(denom,  0, (size_t)N_NODES * 4, stream);
  gemm_kernel<<<GB, 128, 0, stream>>>(h1, W1, hp);
  score_kernel<<<(N_NODES + 3) / 4, 256, 0, stream>>>(hp, as1, ad1, ssrc, sdst);
  alpha_kernel<<<EB, 256, 0, stream>>>(ei, flag, eatt, ssrc, sdst, scal, 1, alpha, maxbuf);
  exp_kernel<<<EB, 256, 0, stream>>>(ei, flag, alpha, maxbuf, wexp, denom);
  agg_kernel<<<N_NODES, 128, 0, stream>>>(rowstart, csr_src, csr_eid, wexp, denom, hp, b1, nullptr, out, 256);
}

// Round 3
// 558.180 us; speedup vs baseline: 1.4840x; 1.1031x over previous
//
#include <hip/hip_runtime.h>
#include <math.h>

#define N_NODES 50000
#define N_EDGES 600000
#define TOT (N_EDGES + N_NODES)   // 650000 edges incl. self-loops
#define HD 128
#define OUTW 384
#define NEG_SLOPE 0.2f

// ---------- helpers ----------

// order-preserving float->uint map for atomicMax-based segment max
static __device__ __forceinline__ unsigned f2o(float f){
  unsigned u = __float_as_uint(f);
  return (u & 0x80000000u) ? ~u : (u | 0x80000000u);
}
static __device__ __forceinline__ float o2f(unsigned o){
  unsigned u = (o & 0x80000000u) ? (o ^ 0x80000000u) : ~o;
  return __uint_as_float(u);
}

// edge_index may arrive as int32 or int64; runtime-detected flag (uniform branch)
static __device__ __forceinline__ int load_edge(const void* ei, int is64, long long off){
  return is64 ? (int)((const long long*)ei)[off] : ((const int*)ei)[off];
}

// ---------- one-time per-launch kernels ----------

__global__ void detect_idx_kernel(const void* ei, int* flag){
  const long long* p = (const long long*)ei;
  int ok = 1;
  for (int i = 0; i < 64; i++){
    long long v = p[i];
    if (v < 0 || v >= N_NODES){ ok = 0; break; }
  }
  *flag = ok;
}

__global__ __launch_bounds__(256) void mean_kernel(const float* __restrict__ ea, float* meansum){
  int tid = blockIdx.x * blockDim.x + threadIdx.x;
  float s = 0.f;
  for (int i = tid; i < N_EDGES; i += gridDim.x * blockDim.x) s += ea[i];
  for (int off = 32; off > 0; off >>= 1) s += __shfl_down(s, off, 64);
  __shared__ float ws[4];
  int lane = threadIdx.x & 63, w = threadIdx.x >> 6;
  if (lane == 0) ws[w] = s;
  __syncthreads();
  if (threadIdx.x == 0){
    atomicAdd(meansum, ws[0] + ws[1] + ws[2] + ws[3]);
  }
}

__global__ __launch_bounds__(128) void ce_kernel(const float* __restrict__ We0, const float* __restrict__ ae0,
                                                 const float* __restrict__ We1, const float* __restrict__ ae1,
                                                 float* scal){
  __shared__ float buf[128];
  int t = threadIdx.x;
  buf[t] = We0[t] * ae0[t];
  __syncthreads();
  for (int off = 64; off > 0; off >>= 1){ if (t < off) buf[t] += buf[t + off]; __syncthreads(); }
  if (t == 0) scal[1] = buf[0];
  __syncthreads();
  buf[t] = We1[t] * ae1[t];
  __syncthreads();
  for (int off = 64; off > 0; off >>= 1){ if (t < off) buf[t] += buf[t + off]; __syncthreads(); }
  if (t == 0) scal[2] = buf[0];
}

__global__ __launch_bounds__(256) void deg_kernel(const void* ei, const int* flag, int* deg){
  int e = blockIdx.x * 256 + threadIdx.x;
  if (e >= TOT) return;
  int is64 = *flag;
  int d = (e < N_EDGES) ? load_edge(ei, is64, (long long)N_EDGES + e) : (e - N_EDGES);
  atomicAdd(&deg[d], 1);
}

// exclusive scan of deg[0..N) -> rowstart, 1024-element chunks
__global__ __launch_bounds__(256) void scan_chunk_kernel(const int* __restrict__ deg,
                                                         int* __restrict__ rowstart,
                                                         int* __restrict__ chunksums){
  __shared__ int sums[256];
  int t = threadIdx.x;
  int base = blockIdx.x * 1024 + t * 4;
  int v[4];
  #pragma unroll
  for (int i = 0; i < 4; i++) v[i] = (base + i < N_NODES) ? deg[base + i] : 0;
  int tsum = v[0] + v[1] + v[2] + v[3];
  sums[t] = tsum;
  __syncthreads();
  for (int off = 1; off < 256; off <<= 1){
    int add = (t >= off) ? sums[t - off] : 0;
    __syncthreads();
    sums[t] += add;
    __syncthreads();
  }
  int run = sums[t] - tsum;
  #pragma unroll
  for (int i = 0; i < 4; i++){
    if (base + i < N_NODES) rowstart[base + i] = run;
    run += v[i];
  }
  if (t == 255) chunksums[blockIdx.x] = sums[255];
}

__global__ void scan_top_kernel(int* chunksums, int nchunks){
  if (threadIdx.x == 0 && blockIdx.x == 0){
    int run = 0;
    for (int c = 0; c < nchunks; c++){ int v = chunksums[c]; chunksums[c] = run; run += v; }
  }
}

__global__ __launch_bounds__(256) void add_off_kernel(int* rowstart, const int* chunksums){
  int base = blockIdx.x * 1024 + threadIdx.x * 4;
  int off = chunksums[blockIdx.x];
  #pragma unroll
  for (int i = 0; i < 4; i++) if (base + i < N_NODES) rowstart[base + i] += off;
}

__global__ __launch_bounds__(256) void fill_kernel(const void* ei, const int* flag,
                                                   const int* __restrict__ rowstart, int* cursor,
                                                   int* __restrict__ csr_src, int* __restrict__ csr_eid){
  int e = blockIdx.x * 256 + threadIdx.x;
  if (e >= TOT) return;
  int is64 = *flag;
  int s, d;
  if (e < N_EDGES){
    s = load_edge(ei, is64, e);
    d = load_edge(ei, is64, (long long)N_EDGES + e);
  } else {
    s = d = e - N_EDGES;
  }
  int pos = rowstart[d] + atomicAdd(&cursor[d], 1);
  csr_src[pos] = s;
  csr_eid[pos] = e;
}

__global__ __launch_bounds__(256) void copyx_kernel(const float* __restrict__ x, float* __restrict__ out){
  int idx = blockIdx.x * 256 + threadIdx.x;   // one float4 per thread
  if (idx >= N_NODES * HD / 4) return;
  int n = idx >> 5;            // 32 float4 per row
  int j4 = idx & 31;
  float4 v = ((const float4*)x)[idx];
  *(float4*)&out[(size_t)n * OUTW + j4 * 4] = v;
}

// ---------- per-layer kernels ----------

// Register-tiled fp32 GEMM: hp[M=50000, 128] = hin[M,128] @ W[128,128]^T
// BM=64 rows/block, BN=128 (all cols), BK=16, 128 threads, 8x8 per thread.
#define BM 64
#define BK 16

__global__ __launch_bounds__(128, 3) void gemm_kernel(const float* __restrict__ hin,
                                                      const float* __restrict__ W,
                                                      float* __restrict__ hp){
  __shared__ float As[BK][BM + 4];    // 16 x 68 floats = 4.25 KB
  __shared__ float Ws[BK][HD + 4];    // 16 x 132 floats = 8.25 KB
  int t  = threadIdx.x;
  int tx = t & 15;          // col group: cols tx*8 .. +7
  int ty = t >> 4;          // row group: rows ty*8 .. +7
  int rb = blockIdx.x * BM;

  float acc[8][8];
  #pragma unroll
  for (int i = 0; i < 8; i++)
    #pragma unroll
    for (int j = 0; j < 8; j++) acc[i][j] = 0.f;

  for (int kb = 0; kb < HD; kb += BK){
    #pragma unroll
    for (int p = 0; p < 2; p++){
      int idx = t + p * 128;          // 0..255
      int row = idx >> 2;             // 0..63
      int kq  = (idx & 3) << 2;       // 0,4,8,12
      int gr  = rb + row;
      if (gr > N_NODES - 1) gr = N_NODES - 1;   // clamp (tail rows never stored)
      float4 v = *(const float4*)&hin[(size_t)gr * HD + kb + kq];
      As[kq + 0][row] = v.x; As[kq + 1][row] = v.y;
      As[kq + 2][row] = v.z; As[kq + 3][row] = v.w;
    }
    #pragma unroll
    for (int p = 0; p < 4; p++){
      int idx = t + p * 128;          // 0..511
      int n   = idx >> 2;             // 0..127
      int kq  = (idx & 3) << 2;
      float4 v = *(const float4*)&W[(size_t)n * HD + kb + kq];
      Ws[kq + 0][n] = v.x; Ws[kq + 1][n] = v.y;
      Ws[kq + 2][n] = v.z; Ws[kq + 3][n] = v.w;
    }
    __syncthreads();
    #pragma unroll
    for (int k = 0; k < BK; k++){
      float a[8], w[8];
      *(float4*)&a[0] = *(const float4*)&As[k][ty * 8];
      *(float4*)&a[4] = *(const float4*)&As[k][ty * 8 + 4];
      *(float4*)&w[0] = *(const float4*)&Ws[k][tx * 8];
      *(float4*)&w[4] = *(const float4*)&Ws[k][tx * 8 + 4];
      #pragma unroll
      for (int i = 0; i < 8; i++)
        #pragma unroll
        for (int j = 0; j < 8; j++)
          acc[i][j] = fmaf(a[i], w[j], acc[i][j]);
    }
    __syncthreads();
  }

  #pragma unroll
  for (int i = 0; i < 8; i++){
    int r = rb + ty * 8 + i;
    if (r < N_NODES){
      float* dst = &hp[(size_t)r * HD + tx * 8];
      *(float4*)&dst[0] = make_float4(acc[i][0], acc[i][1], acc[i][2], acc[i][3]);
      *(float4*)&dst[4] = make_float4(acc[i][4], acc[i][5], acc[i][6], acc[i][7]);
    }
  }
}

// ssrc[n] = dot(hp[n], att_src), sdst[n] = dot(hp[n], att_dst); one wave per node
__global__ __launch_bounds__(256) void score_kernel(const float* __restrict__ hp,
                                                    const float* __restrict__ as_,
                                                    const float* __restrict__ ad_,
                                                    float* __restrict__ ssrc, float* __restrict__ sdst){
  int w = threadIdx.x >> 6, lane = threadIdx.x & 63;
  int n = blockIdx.x * 4 + w;
  if (n >= N_NODES) return;
  const float* row = hp + (size_t)n * HD;
  float a0 = row[lane], a1 = row[64 + lane];
  float ps = a0 * as_[lane] + a1 * as_[64 + lane];
  float pd = a0 * ad_[lane] + a1 * ad_[64 + lane];
  for (int off = 32; off > 0; off >>= 1){
    ps += __shfl_down(ps, off, 64);
    pd += __shfl_down(pd, off, 64);
  }
  if (lane == 0){ ssrc[n] = ps; sdst[n] = pd; }
}

__global__ __launch_bounds__(256) void alpha_kernel(const void* ei, const int* flag,
                                                    const float* __restrict__ eattr,
                                                    const float* __restrict__ ssrc,
                                                    const float* __restrict__ sdst,
                                                    const float* __restrict__ scal, int which,
                                                    float* __restrict__ alpha, unsigned* maxbuf){
  int e = blockIdx.x * 256 + threadIdx.x;
  if (e >= TOT) return;
  int is64 = *flag;
  int s, d; float eav;
  if (e < N_EDGES){
    s = load_edge(ei, is64, e);
    d = load_edge(ei, is64, (long long)N_EDGES + e);
    eav = eattr[e];
  } else {
    s = d = e - N_EDGES;
    eav = scal[0] * (1.0f / (float)N_EDGES);   // mean fill
  }
  float a = ssrc[s] + sdst[d] + eav * scal[1 + which];
  a = (a >= 0.f) ? a : NEG_SLOPE * a;          // leaky_relu
  alpha[e] = a;
  atomicMax(&maxbuf[d], f2o(a));
}

__global__ __launch_bounds__(256) void exp_kernel(const void* ei, const int* flag,
                                                  const float* __restrict__ alpha,
                                                  const unsigned* __restrict__ maxbuf,
                                                  float* __restrict__ wexp, float* __restrict__ denom){
  int e = blockIdx.x * 256 + threadIdx.x;
  if (e >= TOT) return;
  int is64 = *flag;
  int d = (e < N_EDGES) ? load_edge(ei, is64, (long long)N_EDGES + e) : (e - N_EDGES);
  float m = o2f(maxbuf[d]);
  float w = expf(alpha[e] - m);
  wexp[e] = w;
  atomicAdd(&denom[d], w);
}

// one WAVE per dst node (4 nodes / 256-thread block), lane covers 2 cols (float2).
// Edge loop unrolled x4 so 4 independent hp row-gathers are in flight per lane.
__global__ __launch_bounds__(256) void agg_kernel(const int* __restrict__ rowstart,
                                                  const int* __restrict__ csr_src,
                                                  const int* __restrict__ csr_eid,
                                                  const float* __restrict__ wexp,
                                                  const float* __restrict__ denom,
                                                  const float* __restrict__ hp,
                                                  const float* __restrict__ bias,
                                                  float* __restrict__ hnext,
                                                  float* __restrict__ out, int outoff){
  int w    = threadIdx.x >> 6;
  int lane = threadIdx.x & 63;
  int n = blockIdx.x * 4 + w;
  if (n >= N_NODES) return;
  int s0 = rowstart[n];
  int s1 = (n + 1 < N_NODES) ? rowstart[n + 1] : TOT;
  float inv = 1.0f / (denom[n] + 1e-16f);

  float ax = 0.f, ay = 0.f;
  int i = s0;
  for (; i + 4 <= s1; i += 4){
    int sn0 = csr_src[i],     sn1 = csr_src[i + 1];
    int sn2 = csr_src[i + 2], sn3 = csr_src[i + 3];
    int e0 = csr_eid[i],     e1 = csr_eid[i + 1];
    int e2 = csr_eid[i + 2], e3 = csr_eid[i + 3];
    float2 v0 = ((const float2*)(hp + (size_t)sn0 * HD))[lane];
    float2 v1 = ((const float2*)(hp + (size_t)sn1 * HD))[lane];
    float2 v2 = ((const float2*)(hp + (size_t)sn2 * HD))[lane];
    float2 v3 = ((const float2*)(hp + (size_t)sn3 * HD))[lane];
    float p0 = wexp[e0] * inv, p1 = wexp[e1] * inv;
    float p2 = wexp[e2] * inv, p3 = wexp[e3] * inv;
    ax = fmaf(p0, v0.x, ax); ay = fmaf(p0, v0.y, ay);
    ax = fmaf(p1, v1.x, ax); ay = fmaf(p1, v1.y, ay);
    ax = fmaf(p2, v2.x, ax); ay = fmaf(p2, v2.y, ay);
    ax = fmaf(p3, v3.x, ax); ay = fmaf(p3, v3.y, ay);
  }
  for (; i < s1; i++){
    int sn = csr_src[i];
    int e  = csr_eid[i];
    float2 v = ((const float2*)(hp + (size_t)sn * HD))[lane];
    float p = wexp[e] * inv;
    ax = fmaf(p, v.x, ax); ay = fmaf(p, v.y, ay);
  }

  float2 b2 = ((const float2*)bias)[lane];
  float vx = ax + b2.x; vx = vx > 0.f ? vx : 0.f;
  float vy = ay + b2.y; vy = vy > 0.f ? vy : 0.f;
  float2 res = make_float2(vx, vy);
  if (hnext) ((float2*)(hnext + (size_t)n * HD))[lane] = res;
  ((float2*)(out + (size_t)n * OUTW + outoff))[lane] = res;
}

// ---------- launch ----------

extern "C" void kernel_launch(void* const* d_in, const int* in_sizes, int n_in,
                              void* d_out, int out_size, void* d_ws, size_t ws_size,
                              hipStream_t stream){
  (void)in_sizes; (void)n_in; (void)out_size; (void)ws_size;
  const float* x    = (const float*)d_in[0];
  const void*  ei   = d_in[1];
  const float* eatt = (const float*)d_in[2];
  const float* W0   = (const float*)d_in[3];
  const float* as0  = (const float*)d_in[4];
  const float* ad0  = (const float*)d_in[5];
  const float* We0  = (const float*)d_in[6];
  const float* ae0  = (const float*)d_in[7];
  const float* b0   = (const float*)d_in[8];
  const float* W1   = (const float*)d_in[9];
  const float* as1  = (const float*)d_in[10];
  const float* ad1  = (const float*)d_in[11];
  const float* We1  = (const float*)d_in[12];
  const float* ae1  = (const float*)d_in[13];
  const float* b1   = (const float*)d_in[14];
  float* out = (float*)d_out;

  char* ws = (char*)d_ws;
  size_t off = 0;
  auto alloc = [&](size_t bytes) -> void* {
    void* p = ws + off;
    off += (bytes + 255) & ~(size_t)255;
    return p;
  };
  float*    hp       = (float*)   alloc((size_t)N_NODES * HD * 4);
  float*    h1       = (float*)   alloc((size_t)N_NODES * HD * 4);
  float*    ssrc     = (float*)   alloc((size_t)N_NODES * 4);
  float*    sdst     = (float*)   alloc((size_t)N_NODES * 4);
  float*    alpha    = (float*)   alloc((size_t)TOT * 4);
  float*    wexp     = (float*)   alloc((size_t)TOT * 4);
  unsigned* maxbuf   = (unsigned*)alloc((size_t)N_NODES * 4);
  float*    denom    = (float*)   alloc((size_t)N_NODES * 4);
  int*      deg      = (int*)     alloc((size_t)N_NODES * 4);
  int*      rowstart = (int*)     alloc((size_t)N_NODES * 4);
  int*      cursor   = (int*)     alloc((size_t)N_NODES * 4);
  int*      csr_src  = (int*)     alloc((size_t)TOT * 4);
  int*      csr_eid  = (int*)     alloc((size_t)TOT * 4);
  int*      chunksums= (int*)     alloc(64 * 4);
  float*    scal     = (float*)   alloc(64 * 4);   // [0]=sum(edge_attr) [1]=ce0 [2]=ce1
  int*      flag     = (int*)     alloc(64);

  hipMemsetAsync(deg,    0, (size_t)N_NODES * 4, stream);
  hipMemsetAsync(cursor, 0, (size_t)N_NODES * 4, stream);
  hipMemsetAsync(maxbuf, 0, (size_t)N_NODES * 4, stream);
  hipMemsetAsync(denom,  0, (size_t)N_NODES * 4, stream);
  hipMemsetAsync(scal,   0, 64 * 4, stream);

  const int EB = (TOT + 255) / 256;
  const int nchunks = (N_NODES + 1023) / 1024;

  detect_idx_kernel<<<1, 1, 0, stream>>>(ei, flag);
  mean_kernel<<<256, 256, 0, stream>>>(eatt, scal);
  ce_kernel<<<1, 128, 0, stream>>>(We0, ae0, We1, ae1, scal);
  deg_kernel<<<EB, 256, 0, stream>>>(ei, flag, deg);
  scan_chunk_kernel<<<nchunks, 256, 0, stream>>>(deg, rowstart, chunksums);
  scan_top_kernel<<<1, 64, 0, stream>>>(chunksums, nchunks);
  add_off_kernel<<<nchunks, 256, 0, stream>>>(rowstart, chunksums);
  fill_kernel<<<EB, 256, 0, stream>>>(ei, flag, rowstart, cursor, csr_src, csr_eid);
  copyx_kernel<<<(N_NODES * HD / 4 + 255) / 256, 256, 0, stream>>>(x, out);

  const int GB = (N_NODES + BM - 1) / BM;   // 782
  const int AB = (N_NODES + 3) / 4;         // agg blocks

  // layer 0
  gemm_kernel<<<GB, 128, 0, stream>>>(x, W0, hp);
  score_kernel<<<(N_NODES + 3) / 4, 256, 0, stream>>>(hp, as0, ad0, ssrc, sdst);
  alpha_kernel<<<EB, 256, 0, stream>>>(ei, flag, eatt, ssrc, sdst, scal, 0, alpha, maxbuf);
  exp_kernel<<<EB, 256, 0, stream>>>(ei, flag, alpha, maxbuf, wexp, denom);
  agg_kernel<<<AB, 256, 0, stream>>>(rowstart, csr_src, csr_eid, wexp, denom, hp, b0, h1, out, 128);

  // layer 1
  hipMemsetAsync(maxbuf, 0, (size_t)N_NODES * 4, stream);
  hipMemsetAsync(denom,  0, (size_t)N_NODES * 4, stream);
  gemm_kernel<<<GB, 128, 0, stream>>>(h1, W1, hp);
  score_kernel<<<(N_NODES + 3) / 4, 256, 0, stream>>>(hp, as1, ad1, ssrc, sdst);
  alpha_kernel<<<EB, 256, 0, stream>>>(ei, flag, eatt, ssrc, sdst, scal, 1, alpha, maxbuf);
  exp_kernel<<<EB, 256, 0, stream>>>(ei, flag, alpha, maxbuf, wexp, denom);
  agg_kernel<<<AB, 256, 0, stream>>>(rowstart, csr_src, csr_eid, wexp, denom, hp, b1, nullptr, out, 256);
}

// Round 4
// 451.868 us; speedup vs baseline: 1.8331x; 1.2353x over previous
//
#include <hip/hip_runtime.h>
#include <hip/hip_fp16.h>
#include <math.h>

#define N_NODES 50000
#define N_EDGES 600000
#define TOT (N_EDGES + N_NODES)   // 650000 edges incl. self-loops
#define HD 128
#define OUTW 384
#define NEG_SLOPE 0.2f

// ---------- helpers ----------

// edge_index may arrive as int32 or int64; runtime-detected flag (uniform branch)
static __device__ __forceinline__ int load_edge(const void* ei, int is64, long long off){
  return is64 ? (int)((const long long*)ei)[off] : ((const int*)ei)[off];
}

// ---------- one-time per-launch kernels ----------

__global__ void detect_idx_kernel(const void* ei, int* flag){
  const long long* p = (const long long*)ei;
  int ok = 1;
  for (int i = 0; i < 64; i++){
    long long v = p[i];
    if (v < 0 || v >= N_NODES){ ok = 0; break; }
  }
  *flag = ok;
}

__global__ __launch_bounds__(256) void mean_kernel(const float* __restrict__ ea, float* meansum){
  int tid = blockIdx.x * blockDim.x + threadIdx.x;
  float s = 0.f;
  for (int i = tid; i < N_EDGES; i += gridDim.x * blockDim.x) s += ea[i];
  for (int off = 32; off > 0; off >>= 1) s += __shfl_down(s, off, 64);
  __shared__ float ws[4];
  int lane = threadIdx.x & 63, w = threadIdx.x >> 6;
  if (lane == 0) ws[w] = s;
  __syncthreads();
  if (threadIdx.x == 0){
    atomicAdd(meansum, ws[0] + ws[1] + ws[2] + ws[3]);
  }
}

__global__ __launch_bounds__(128) void ce_kernel(const float* __restrict__ We0, const float* __restrict__ ae0,
                                                 const float* __restrict__ We1, const float* __restrict__ ae1,
                                                 float* scal){
  __shared__ float buf[128];
  int t = threadIdx.x;
  buf[t] = We0[t] * ae0[t];
  __syncthreads();
  for (int off = 64; off > 0; off >>= 1){ if (t < off) buf[t] += buf[t + off]; __syncthreads(); }
  if (t == 0) scal[1] = buf[0];
  __syncthreads();
  buf[t] = We1[t] * ae1[t];
  __syncthreads();
  for (int off = 64; off > 0; off >>= 1){ if (t < off) buf[t] += buf[t + off]; __syncthreads(); }
  if (t == 0) scal[2] = buf[0];
}

__global__ __launch_bounds__(256) void deg_kernel(const void* ei, const int* flag, int* deg){
  int e = blockIdx.x * 256 + threadIdx.x;
  if (e >= TOT) return;
  int is64 = *flag;
  int d = (e < N_EDGES) ? load_edge(ei, is64, (long long)N_EDGES + e) : (e - N_EDGES);
  atomicAdd(&deg[d], 1);
}

// exclusive scan of deg[0..N) -> rowstart, 1024-element chunks
__global__ __launch_bounds__(256) void scan_chunk_kernel(const int* __restrict__ deg,
                                                         int* __restrict__ rowstart,
                                                         int* __restrict__ chunksums){
  __shared__ int sums[256];
  int t = threadIdx.x;
  int base = blockIdx.x * 1024 + t * 4;
  int v[4];
  #pragma unroll
  for (int i = 0; i < 4; i++) v[i] = (base + i < N_NODES) ? deg[base + i] : 0;
  int tsum = v[0] + v[1] + v[2] + v[3];
  sums[t] = tsum;
  __syncthreads();
  for (int off = 1; off < 256; off <<= 1){
    int add = (t >= off) ? sums[t - off] : 0;
    __syncthreads();
    sums[t] += add;
    __syncthreads();
  }
  int run = sums[t] - tsum;
  #pragma unroll
  for (int i = 0; i < 4; i++){
    if (base + i < N_NODES) rowstart[base + i] = run;
    run += v[i];
  }
  if (t == 255) chunksums[blockIdx.x] = sums[255];
}

__global__ void scan_top_kernel(int* chunksums, int nchunks){
  if (threadIdx.x == 0 && blockIdx.x == 0){
    int run = 0;
    for (int c = 0; c < nchunks; c++){ int v = chunksums[c]; chunksums[c] = run; run += v; }
  }
}

__global__ __launch_bounds__(256) void add_off_kernel(int* rowstart, const int* chunksums){
  int base = blockIdx.x * 1024 + threadIdx.x * 4;
  int off = chunksums[blockIdx.x];
  #pragma unroll
  for (int i = 0; i < 4; i++) if (base + i < N_NODES) rowstart[base + i] += off;
}

__global__ __launch_bounds__(256) void fill_kernel(const void* ei, const int* flag,
                                                   const int* __restrict__ rowstart, int* cursor,
                                                   int* __restrict__ csr_src, int* __restrict__ csr_eid){
  int e = blockIdx.x * 256 + threadIdx.x;
  if (e >= TOT) return;
  int is64 = *flag;
  int s, d;
  if (e < N_EDGES){
    s = load_edge(ei, is64, e);
    d = load_edge(ei, is64, (long long)N_EDGES + e);
  } else {
    s = d = e - N_EDGES;
  }
  int pos = rowstart[d] + atomicAdd(&cursor[d], 1);
  csr_src[pos] = s;
  csr_eid[pos] = e;
}

__global__ __launch_bounds__(256) void copyx_kernel(const float* __restrict__ x, float* __restrict__ out){
  int idx = blockIdx.x * 256 + threadIdx.x;   // one float4 per thread
  if (idx >= N_NODES * HD / 4) return;
  int n = idx >> 5;            // 32 float4 per row
  int j4 = idx & 31;
  float4 v = ((const float4*)x)[idx];
  *(float4*)&out[(size_t)n * OUTW + j4 * 4] = v;
}

// ---------- per-layer kernels ----------

// Register-tiled fp32 GEMM: hp_h[M=50000, 128] = fp16( hin[M,128] @ W[128,128]^T )
// BM=64 rows/block, BN=128 (all cols), BK=16, 128 threads, 8x8 per thread.
#define BM 64
#define BK 16

struct __align__(16) H8 { __half2 a, b, c, d; };

__global__ __launch_bounds__(128, 3) void gemm_kernel(const float* __restrict__ hin,
                                                      const float* __restrict__ W,
                                                      __half* __restrict__ hp_h){
  __shared__ float As[BK][BM + 4];    // 16 x 68 floats = 4.25 KB
  __shared__ float Ws[BK][HD + 4];    // 16 x 132 floats = 8.25 KB
  int t  = threadIdx.x;
  int tx = t & 15;          // col group: cols tx*8 .. +7
  int ty = t >> 4;          // row group: rows ty*8 .. +7
  int rb = blockIdx.x * BM;

  float acc[8][8];
  #pragma unroll
  for (int i = 0; i < 8; i++)
    #pragma unroll
    for (int j = 0; j < 8; j++) acc[i][j] = 0.f;

  for (int kb = 0; kb < HD; kb += BK){
    #pragma unroll
    for (int p = 0; p < 2; p++){
      int idx = t + p * 128;          // 0..255
      int row = idx >> 2;             // 0..63
      int kq  = (idx & 3) << 2;       // 0,4,8,12
      int gr  = rb + row;
      if (gr > N_NODES - 1) gr = N_NODES - 1;   // clamp (tail rows never stored)
      float4 v = *(const float4*)&hin[(size_t)gr * HD + kb + kq];
      As[kq + 0][row] = v.x; As[kq + 1][row] = v.y;
      As[kq + 2][row] = v.z; As[kq + 3][row] = v.w;
    }
    #pragma unroll
    for (int p = 0; p < 4; p++){
      int idx = t + p * 128;          // 0..511
      int n   = idx >> 2;             // 0..127
      int kq  = (idx & 3) << 2;
      float4 v = *(const float4*)&W[(size_t)n * HD + kb + kq];
      Ws[kq + 0][n] = v.x; Ws[kq + 1][n] = v.y;
      Ws[kq + 2][n] = v.z; Ws[kq + 3][n] = v.w;
    }
    __syncthreads();
    #pragma unroll
    for (int k = 0; k < BK; k++){
      float a[8], w[8];
      *(float4*)&a[0] = *(const float4*)&As[k][ty * 8];
      *(float4*)&a[4] = *(const float4*)&As[k][ty * 8 + 4];
      *(float4*)&w[0] = *(const float4*)&Ws[k][tx * 8];
      *(float4*)&w[4] = *(const float4*)&Ws[k][tx * 8 + 4];
      #pragma unroll
      for (int i = 0; i < 8; i++)
        #pragma unroll
        for (int j = 0; j < 8; j++)
          acc[i][j] = fmaf(a[i], w[j], acc[i][j]);
    }
    __syncthreads();
  }

  #pragma unroll
  for (int i = 0; i < 8; i++){
    int r = rb + ty * 8 + i;
    if (r < N_NODES){
      H8 pk;
      pk.a = __floats2half2_rn(acc[i][0], acc[i][1]);
      pk.b = __floats2half2_rn(acc[i][2], acc[i][3]);
      pk.c = __floats2half2_rn(acc[i][4], acc[i][5]);
      pk.d = __floats2half2_rn(acc[i][6], acc[i][7]);
      *(H8*)&hp_h[(size_t)r * HD + tx * 8] = pk;
    }
  }
}

// ssrc[n] = dot(hp[n], att_src), sdst[n] = dot(hp[n], att_dst); one wave per node, fp16 hp
__global__ __launch_bounds__(256) void score_kernel(const __half* __restrict__ hp_h,
                                                    const float* __restrict__ as_,
                                                    const float* __restrict__ ad_,
                                                    float* __restrict__ ssrc, float* __restrict__ sdst){
  int w = threadIdx.x >> 6, lane = threadIdx.x & 63;
  int n = blockIdx.x * 4 + w;
  if (n >= N_NODES) return;
  const __half2* row = (const __half2*)(hp_h + (size_t)n * HD);
  float2 v  = __half22float2(row[lane]);            // cols 2*lane, 2*lane+1
  float2 sA = ((const float2*)as_)[lane];
  float2 sD = ((const float2*)ad_)[lane];
  float ps = v.x * sA.x + v.y * sA.y;
  float pd = v.x * sD.x + v.y * sD.y;
  for (int off = 32; off > 0; off >>= 1){
    ps += __shfl_down(ps, off, 64);
    pd += __shfl_down(pd, off, 64);
  }
  if (lane == 0){ ssrc[n] = ps; sdst[n] = pd; }
}

// fused alpha + exp (no max-subtraction; |alpha| small enough that exp() is safe in fp32)
__global__ __launch_bounds__(256) void edge_kernel(const void* ei, const int* flag,
                                                   const float* __restrict__ eattr,
                                                   const float* __restrict__ ssrc,
                                                   const float* __restrict__ sdst,
                                                   const float* __restrict__ scal, int which,
                                                   float* __restrict__ wexp, float* __restrict__ denom){
  int e = blockIdx.x * 256 + threadIdx.x;
  if (e >= TOT) return;
  int is64 = *flag;
  int s, d; float eav;
  if (e < N_EDGES){
    s = load_edge(ei, is64, e);
    d = load_edge(ei, is64, (long long)N_EDGES + e);
    eav = eattr[e];
  } else {
    s = d = e - N_EDGES;
    eav = scal[0] * (1.0f / (float)N_EDGES);   // mean fill
  }
  float a = ssrc[s] + sdst[d] + eav * scal[1 + which];
  a = (a >= 0.f) ? a : NEG_SLOPE * a;          // leaky_relu
  float w = expf(a);
  wexp[e] = w;
  atomicAdd(&denom[d], w);
}

// aggregation: 32 lanes per dst node (2 nodes per wave, 8 per 256-block),
// lane covers 4 cols (half4 = 8B), edge loop unrolled x4 -> 8 independent
// row-gathers in flight per wave.
__global__ __launch_bounds__(256) void agg_kernel(const int* __restrict__ rowstart,
                                                  const int* __restrict__ csr_src,
                                                  const int* __restrict__ csr_eid,
                                                  const float* __restrict__ wexp,
                                                  const float* __restrict__ denom,
                                                  const __half* __restrict__ hp_h,
                                                  const float* __restrict__ bias,
                                                  float* __restrict__ hnext,
                                                  float* __restrict__ out, int outoff){
  int sub  = threadIdx.x >> 5;     // 0..7 : node slot within block
  int lane = threadIdx.x & 31;     // covers cols 4*lane .. +3
  int n = blockIdx.x * 8 + sub;
  if (n >= N_NODES) return;
  int s0 = rowstart[n];
  int s1 = (n + 1 < N_NODES) ? rowstart[n + 1] : TOT;
  float inv = 1.0f / (denom[n] + 1e-16f);
  const float2* hb = (const float2*)hp_h;   // one float2 = 4 halves; row stride = 32

  float a0 = 0.f, a1 = 0.f, a2 = 0.f, a3 = 0.f;
  int i = s0;
  for (; i + 4 <= s1; i += 4){
    int sn0 = csr_src[i],     sn1 = csr_src[i + 1];
    int sn2 = csr_src[i + 2], sn3 = csr_src[i + 3];
    int e0 = csr_eid[i],     e1 = csr_eid[i + 1];
    int e2 = csr_eid[i + 2], e3 = csr_eid[i + 3];
    float2 r0 = hb[(size_t)sn0 * 32 + lane];
    float2 r1 = hb[(size_t)sn1 * 32 + lane];
    float2 r2 = hb[(size_t)sn2 * 32 + lane];
    float2 r3 = hb[(size_t)sn3 * 32 + lane];
    float p0 = wexp[e0] * inv, p1 = wexp[e1] * inv;
    float p2 = wexp[e2] * inv, p3 = wexp[e3] * inv;
    float2 f;
    f = __half22float2(*(__half2*)&r0.x); a0 = fmaf(p0, f.x, a0); a1 = fmaf(p0, f.y, a1);
    f = __half22float2(*(__half2*)&r0.y); a2 = fmaf(p0, f.x, a2); a3 = fmaf(p0, f.y, a3);
    f = __half22float2(*(__half2*)&r1.x); a0 = fmaf(p1, f.x, a0); a1 = fmaf(p1, f.y, a1);
    f = __half22float2(*(__half2*)&r1.y); a2 = fmaf(p1, f.x, a2); a3 = fmaf(p1, f.y, a3);
    f = __half22float2(*(__half2*)&r2.x); a0 = fmaf(p2, f.x, a0); a1 = fmaf(p2, f.y, a1);
    f = __half22float2(*(__half2*)&r2.y); a2 = fmaf(p2, f.x, a2); a3 = fmaf(p2, f.y, a3);
    f = __half22float2(*(__half2*)&r3.x); a0 = fmaf(p3, f.x, a0); a1 = fmaf(p3, f.y, a1);
    f = __half22float2(*(__half2*)&r3.y); a2 = fmaf(p3, f.x, a2); a3 = fmaf(p3, f.y, a3);
  }
  for (; i < s1; i++){
    int sn = csr_src[i];
    int e  = csr_eid[i];
    float2 r = hb[(size_t)sn * 32 + lane];
    float p = wexp[e] * inv;
    float2 f;
    f = __half22float2(*(__half2*)&r.x); a0 = fmaf(p, f.x, a0); a1 = fmaf(p, f.y, a1);
    f = __half22float2(*(__half2*)&r.y); a2 = fmaf(p, f.x, a2); a3 = fmaf(p, f.y, a3);
  }

  float4 b4 = *(const float4*)&bias[lane * 4];
  float v0 = a0 + b4.x; v0 = v0 > 0.f ? v0 : 0.f;
  float v1 = a1 + b4.y; v1 = v1 > 0.f ? v1 : 0.f;
  float v2 = a2 + b4.z; v2 = v2 > 0.f ? v2 : 0.f;
  float v3 = a3 + b4.w; v3 = v3 > 0.f ? v3 : 0.f;
  float4 res = make_float4(v0, v1, v2, v3);
  if (hnext) *(float4*)&hnext[(size_t)n * HD + lane * 4] = res;
  *(float4*)&out[(size_t)n * OUTW + outoff + lane * 4] = res;
}

// ---------- launch ----------

extern "C" void kernel_launch(void* const* d_in, const int* in_sizes, int n_in,
                              void* d_out, int out_size, void* d_ws, size_t ws_size,
                              hipStream_t stream){
  (void)in_sizes; (void)n_in; (void)out_size; (void)ws_size;
  const float* x    = (const float*)d_in[0];
  const void*  ei   = d_in[1];
  const float* eatt = (const float*)d_in[2];
  const float* W0   = (const float*)d_in[3];
  const float* as0  = (const float*)d_in[4];
  const float* ad0  = (const float*)d_in[5];
  const float* We0  = (const float*)d_in[6];
  const float* ae0  = (const float*)d_in[7];
  const float* b0   = (const float*)d_in[8];
  const float* W1   = (const float*)d_in[9];
  const float* as1  = (const float*)d_in[10];
  const float* ad1  = (const float*)d_in[11];
  const float* We1  = (const float*)d_in[12];
  const float* ae1  = (const float*)d_in[13];
  const float* b1   = (const float*)d_in[14];
  float* out = (float*)d_out;

  char* ws = (char*)d_ws;
  size_t off = 0;
  auto alloc = [&](size_t bytes) -> void* {
    void* p = ws + off;
    off += (bytes + 255) & ~(size_t)255;
    return p;
  };
  __half*   hp_h     = (__half*)  alloc((size_t)N_NODES * HD * 2);
  float*    h1       = (float*)   alloc((size_t)N_NODES * HD * 4);
  float*    ssrc     = (float*)   alloc((size_t)N_NODES * 4);
  float*    sdst     = (float*)   alloc((size_t)N_NODES * 4);
  float*    wexp     = (float*)   alloc((size_t)TOT * 4);
  float*    denom    = (float*)   alloc((size_t)N_NODES * 2 * 4);  // two layers
  int*      deg      = (int*)     alloc((size_t)N_NODES * 4);
  int*      rowstart = (int*)     alloc((size_t)N_NODES * 4);
  int*      cursor   = (int*)     alloc((size_t)N_NODES * 4);
  int*      csr_src  = (int*)     alloc((size_t)TOT * 4);
  int*      csr_eid  = (int*)     alloc((size_t)TOT * 4);
  int*      chunksums= (int*)     alloc(64 * 4);
  float*    scal     = (float*)   alloc(64 * 4);   // [0]=sum(edge_attr) [1]=ce0 [2]=ce1
  int*      flag     = (int*)     alloc(64);
  float*    denom0   = denom;
  float*    denom1   = denom + N_NODES;

  hipMemsetAsync(deg,    0, (size_t)N_NODES * 4, stream);
  hipMemsetAsync(cursor, 0, (size_t)N_NODES * 4, stream);
  hipMemsetAsync(denom,  0, (size_t)N_NODES * 2 * 4, stream);
  hipMemsetAsync(scal,   0, 64 * 4, stream);

  const int EB = (TOT + 255) / 256;
  const int nchunks = (N_NODES + 1023) / 1024;

  detect_idx_kernel<<<1, 1, 0, stream>>>(ei, flag);
  mean_kernel<<<256, 256, 0, stream>>>(eatt, scal);
  ce_kernel<<<1, 128, 0, stream>>>(We0, ae0, We1, ae1, scal);
  deg_kernel<<<EB, 256, 0, stream>>>(ei, flag, deg);
  scan_chunk_kernel<<<nchunks, 256, 0, stream>>>(deg, rowstart, chunksums);
  scan_top_kernel<<<1, 64, 0, stream>>>(chunksums, nchunks);
  add_off_kernel<<<nchunks, 256, 0, stream>>>(rowstart, chunksums);
  fill_kernel<<<EB, 256, 0, stream>>>(ei, flag, rowstart, cursor, csr_src, csr_eid);
  copyx_kernel<<<(N_NODES * HD / 4 + 255) / 256, 256, 0, stream>>>(x, out);

  const int GB = (N_NODES + BM - 1) / BM;   // 782
  const int AB = (N_NODES + 7) / 8;         // agg blocks (8 nodes per block)

  // layer 0
  gemm_kernel<<<GB, 128, 0, stream>>>(x, W0, hp_h);
  score_kernel<<<(N_NODES + 3) / 4, 256, 0, stream>>>(hp_h, as0, ad0, ssrc, sdst);
  edge_kernel<<<EB, 256, 0, stream>>>(ei, flag, eatt, ssrc, sdst, scal, 0, wexp, denom0);
  agg_kernel<<<AB, 256, 0, stream>>>(rowstart, csr_src, csr_eid, wexp, denom0, hp_h, b0, h1, out, 128);

  // layer 1
  gemm_kernel<<<GB, 128, 0, stream>>>(h1, W1, hp_h);
  score_kernel<<<(N_NODES + 3) / 4, 256, 0, stream>>>(hp_h, as1, ad1, ssrc, sdst);
  edge_kernel<<<EB, 256, 0, stream>>>(ei, flag, eatt, ssrc, sdst, scal, 1, wexp, denom1);
  agg_kernel<<<AB, 256, 0, stream>>>(rowstart, csr_src, csr_eid, wexp, denom1, hp_h, b1, nullptr, out, 256);
}

// Round 5
// 446.949 us; speedup vs baseline: 1.8533x; 1.0110x over previous
//
#include <hip/hip_runtime.h>
#include <hip/hip_fp16.h>
#include <math.h>
#include <type_traits>

#define N_NODES 50000
#define N_EDGES 600000
#define TOT (N_EDGES + N_NODES)   // 650000 edges incl. self-loops
#define HD 128
#define OUTW 384
#define NEG_SLOPE 0.2f

// ---------- helpers ----------

// edge_index may arrive as int32 or int64; runtime-detected flag (uniform branch)
static __device__ __forceinline__ int load_edge(const void* ei, int is64, long long off){
  return is64 ? (int)((const long long*)ei)[off] : ((const int*)ei)[off];
}

// ---------- one-time per-launch kernels ----------

__global__ void detect_idx_kernel(const void* ei, int* flag){
  const long long* p = (const long long*)ei;
  int ok = 1;
  for (int i = 0; i < 64; i++){
    long long v = p[i];
    if (v < 0 || v >= N_NODES){ ok = 0; break; }
  }
  *flag = ok;
}

__global__ __launch_bounds__(256) void mean_kernel(const float* __restrict__ ea, float* meansum){
  int tid = blockIdx.x * blockDim.x + threadIdx.x;
  float s = 0.f;
  for (int i = tid; i < N_EDGES; i += gridDim.x * blockDim.x) s += ea[i];
  for (int off = 32; off > 0; off >>= 1) s += __shfl_down(s, off, 64);
  __shared__ float ws[4];
  int lane = threadIdx.x & 63, w = threadIdx.x >> 6;
  if (lane == 0) ws[w] = s;
  __syncthreads();
  if (threadIdx.x == 0){
    atomicAdd(meansum, ws[0] + ws[1] + ws[2] + ws[3]);
  }
}

__global__ __launch_bounds__(128) void ce_kernel(const float* __restrict__ We0, const float* __restrict__ ae0,
                                                 const float* __restrict__ We1, const float* __restrict__ ae1,
                                                 float* scal){
  __shared__ float buf[128];
  int t = threadIdx.x;
  buf[t] = We0[t] * ae0[t];
  __syncthreads();
  for (int off = 64; off > 0; off >>= 1){ if (t < off) buf[t] += buf[t + off]; __syncthreads(); }
  if (t == 0) scal[1] = buf[0];
  __syncthreads();
  buf[t] = We1[t] * ae1[t];
  __syncthreads();
  for (int off = 64; off > 0; off >>= 1){ if (t < off) buf[t] += buf[t + off]; __syncthreads(); }
  if (t == 0) scal[2] = buf[0];
}

// degree count + one-time int64 -> int32 src/dst decode (coalesced write)
__global__ __launch_bounds__(256) void degconv_kernel(const void* ei, const int* flag, int* deg,
                                                      int* __restrict__ src32, int* __restrict__ dst32){
  int e = blockIdx.x * 256 + threadIdx.x;
  if (e >= TOT) return;
  int is64 = *flag;
  int d;
  if (e < N_EDGES){
    int s = load_edge(ei, is64, e);
    d = load_edge(ei, is64, (long long)N_EDGES + e);
    src32[e] = s;
    dst32[e] = d;
  } else {
    d = e - N_EDGES;
  }
  atomicAdd(&deg[d], 1);
}

// exclusive scan of deg[0..N) -> rowstart, 1024-element chunks
__global__ __launch_bounds__(256) void scan_chunk_kernel(const int* __restrict__ deg,
                                                         int* __restrict__ rowstart,
                                                         int* __restrict__ chunksums){
  __shared__ int sums[256];
  int t = threadIdx.x;
  int base = blockIdx.x * 1024 + t * 4;
  int v[4];
  #pragma unroll
  for (int i = 0; i < 4; i++) v[i] = (base + i < N_NODES) ? deg[base + i] : 0;
  int tsum = v[0] + v[1] + v[2] + v[3];
  sums[t] = tsum;
  __syncthreads();
  for (int off = 1; off < 256; off <<= 1){
    int add = (t >= off) ? sums[t - off] : 0;
    __syncthreads();
    sums[t] += add;
    __syncthreads();
  }
  int run = sums[t] - tsum;
  #pragma unroll
  for (int i = 0; i < 4; i++){
    if (base + i < N_NODES) rowstart[base + i] = run;
    run += v[i];
  }
  if (t == 255) chunksums[blockIdx.x] = sums[255];
}

__global__ void scan_top_kernel(int* chunksums, int nchunks){
  if (threadIdx.x == 0 && blockIdx.x == 0){
    int run = 0;
    for (int c = 0; c < nchunks; c++){ int v = chunksums[c]; chunksums[c] = run; run += v; }
  }
}

// add chunk offsets; also emit a second copy (rowcur) used as the fill cursor
__global__ __launch_bounds__(256) void add_off_kernel(int* rowstart, int* rowcur, const int* chunksums){
  int base = blockIdx.x * 1024 + threadIdx.x * 4;
  int off = chunksums[blockIdx.x];
  #pragma unroll
  for (int i = 0; i < 4; i++){
    if (base + i < N_NODES){
      int v = rowstart[base + i] + off;
      rowstart[base + i] = v;
      rowcur[base + i] = v;
    }
  }
}

// bucket fill: one packed int2 (src, eid) scattered store per edge
__global__ __launch_bounds__(256) void fill_kernel(const int* __restrict__ src32,
                                                   const int* __restrict__ dst32,
                                                   int* rowcur, int2* __restrict__ csr){
  int e = blockIdx.x * 256 + threadIdx.x;
  if (e >= TOT) return;
  int s, d;
  if (e < N_EDGES){
    s = src32[e];
    d = dst32[e];
  } else {
    s = d = e - N_EDGES;
  }
  int pos = atomicAdd(&rowcur[d], 1);
  csr[pos] = make_int2(s, e);
}

__global__ __launch_bounds__(256) void copyx_kernel(const float* __restrict__ x, float* __restrict__ out){
  int idx = blockIdx.x * 256 + threadIdx.x;   // one float4 per thread
  if (idx >= N_NODES * HD / 4) return;
  int n = idx >> 5;            // 32 float4 per row
  int j4 = idx & 31;
  float4 v = ((const float4*)x)[idx];
  *(float4*)&out[(size_t)n * OUTW + j4 * 4] = v;
}

// ---------- per-layer kernels ----------

// Register-tiled GEMM: hp_h[M,128] = fp16( hin[M,128] @ W[128,128]^T ), input fp32 or fp16.
// BM=64 rows/block, BN=128, BK=16, 128 threads, 8x8 per thread.
#define BM 64
#define BK 16

struct __align__(16) H8 { __half2 a, b, c, d; };

template <typename T>
__global__ __launch_bounds__(128, 3) void gemm_kernel(const T* __restrict__ hin,
                                                      const float* __restrict__ W,
                                                      __half* __restrict__ hp_h){
  __shared__ float As[BK][BM + 4];    // 16 x 68 floats = 4.25 KB
  __shared__ float Ws[BK][HD + 4];    // 16 x 132 floats = 8.25 KB
  int t  = threadIdx.x;
  int tx = t & 15;          // col group: cols tx*8 .. +7
  int ty = t >> 4;          // row group: rows ty*8 .. +7
  int rb = blockIdx.x * BM;

  float acc[8][8];
  #pragma unroll
  for (int i = 0; i < 8; i++)
    #pragma unroll
    for (int j = 0; j < 8; j++) acc[i][j] = 0.f;

  for (int kb = 0; kb < HD; kb += BK){
    #pragma unroll
    for (int p = 0; p < 2; p++){
      int idx = t + p * 128;          // 0..255
      int row = idx >> 2;             // 0..63
      int kq  = (idx & 3) << 2;       // 0,4,8,12
      int gr  = rb + row;
      if (gr > N_NODES - 1) gr = N_NODES - 1;   // clamp (tail rows never stored)
      float vx, vy, vz, vw;
      if constexpr (std::is_same<T, float>::value){
        float4 v = *(const float4*)&hin[(size_t)gr * HD + kb + kq];
        vx = v.x; vy = v.y; vz = v.z; vw = v.w;
      } else {
        float2 raw = *(const float2*)&hin[(size_t)gr * HD + kb + kq];  // 4 halves
        const __half2* h2 = (const __half2*)&raw;
        float2 f0 = __half22float2(h2[0]);
        float2 f1 = __half22float2(h2[1]);
        vx = f0.x; vy = f0.y; vz = f1.x; vw = f1.y;
      }
      As[kq + 0][row] = vx; As[kq + 1][row] = vy;
      As[kq + 2][row] = vz; As[kq + 3][row] = vw;
    }
    #pragma unroll
    for (int p = 0; p < 4; p++){
      int idx = t + p * 128;          // 0..511
      int n   = idx >> 2;             // 0..127
      int kq  = (idx & 3) << 2;
      float4 v = *(const float4*)&W[(size_t)n * HD + kb + kq];
      Ws[kq + 0][n] = v.x; Ws[kq + 1][n] = v.y;
      Ws[kq + 2][n] = v.z; Ws[kq + 3][n] = v.w;
    }
    __syncthreads();
    #pragma unroll
    for (int k = 0; k < BK; k++){
      float a[8], w[8];
      *(float4*)&a[0] = *(const float4*)&As[k][ty * 8];
      *(float4*)&a[4] = *(const float4*)&As[k][ty * 8 + 4];
      *(float4*)&w[0] = *(const float4*)&Ws[k][tx * 8];
      *(float4*)&w[4] = *(const float4*)&Ws[k][tx * 8 + 4];
      #pragma unroll
      for (int i = 0; i < 8; i++)
        #pragma unroll
        for (int j = 0; j < 8; j++)
          acc[i][j] = fmaf(a[i], w[j], acc[i][j]);
    }
    __syncthreads();
  }

  #pragma unroll
  for (int i = 0; i < 8; i++){
    int r = rb + ty * 8 + i;
    if (r < N_NODES){
      H8 pk;
      pk.a = __floats2half2_rn(acc[i][0], acc[i][1]);
      pk.b = __floats2half2_rn(acc[i][2], acc[i][3]);
      pk.c = __floats2half2_rn(acc[i][4], acc[i][5]);
      pk.d = __floats2half2_rn(acc[i][6], acc[i][7]);
      *(H8*)&hp_h[(size_t)r * HD + tx * 8] = pk;
    }
  }
}

// ssrc[n] = dot(hp[n], att_src), sdst[n] = dot(hp[n], att_dst); one wave per node, fp16 hp
__global__ __launch_bounds__(256) void score_kernel(const __half* __restrict__ hp_h,
                                                    const float* __restrict__ as_,
                                                    const float* __restrict__ ad_,
                                                    float* __restrict__ ssrc, float* __restrict__ sdst){
  int w = threadIdx.x >> 6, lane = threadIdx.x & 63;
  int n = blockIdx.x * 4 + w;
  if (n >= N_NODES) return;
  const __half2* row = (const __half2*)(hp_h + (size_t)n * HD);
  float2 v  = __half22float2(row[lane]);            // cols 2*lane, 2*lane+1
  float2 sA = ((const float2*)as_)[lane];
  float2 sD = ((const float2*)ad_)[lane];
  float ps = v.x * sA.x + v.y * sA.y;
  float pd = v.x * sD.x + v.y * sD.y;
  for (int off = 32; off > 0; off >>= 1){
    ps += __shfl_down(ps, off, 64);
    pd += __shfl_down(pd, off, 64);
  }
  if (lane == 0){ ssrc[n] = ps; sdst[n] = pd; }
}

// fused alpha + exp (no max-subtraction; |alpha| small enough that exp() is safe in fp32)
__global__ __launch_bounds__(256) void edge_kernel(const int* __restrict__ src32,
                                                   const int* __restrict__ dst32,
                                                   const float* __restrict__ eattr,
                                                   const float* __restrict__ ssrc,
                                                   const float* __restrict__ sdst,
                                                   const float* __restrict__ scal, int which,
                                                   float* __restrict__ wexp, float* __restrict__ denom){
  int e = blockIdx.x * 256 + threadIdx.x;
  if (e >= TOT) return;
  int s, d; float eav;
  if (e < N_EDGES){
    s = src32[e];
    d = dst32[e];
    eav = eattr[e];
  } else {
    s = d = e - N_EDGES;
    eav = scal[0] * (1.0f / (float)N_EDGES);   // mean fill
  }
  float a = ssrc[s] + sdst[d] + eav * scal[1 + which];
  a = (a >= 0.f) ? a : NEG_SLOPE * a;          // leaky_relu
  float w = expf(a);
  wexp[e] = w;
  atomicAdd(&denom[d], w);
}

// aggregation: 32 lanes per dst node (2 nodes per wave, 8 per 256-block),
// lane covers 4 cols (half4 = 8B), edge loop unrolled x4.
// hnext (layer-1 input) stored fp16; out always fp32 from the fp32 accumulator.
__global__ __launch_bounds__(256) void agg_kernel(const int* __restrict__ rowstart,
                                                  const int2* __restrict__ csr,
                                                  const float* __restrict__ wexp,
                                                  const float* __restrict__ denom,
                                                  const __half* __restrict__ hp_h,
                                                  const float* __restrict__ bias,
                                                  __half* __restrict__ hnext,
                                                  float* __restrict__ out, int outoff){
  int sub  = threadIdx.x >> 5;     // 0..7 : node slot within block
  int lane = threadIdx.x & 31;     // covers cols 4*lane .. +3
  int n = blockIdx.x * 8 + sub;
  if (n >= N_NODES) return;
  int s0 = rowstart[n];
  int s1 = (n + 1 < N_NODES) ? rowstart[n + 1] : TOT;
  float inv = 1.0f / (denom[n] + 1e-16f);
  const float2* hb = (const float2*)hp_h;   // one float2 = 4 halves; row stride = 32

  float a0 = 0.f, a1 = 0.f, a2 = 0.f, a3 = 0.f;
  int i = s0;
  for (; i + 4 <= s1; i += 4){
    int2 se0 = csr[i],     se1 = csr[i + 1];
    int2 se2 = csr[i + 2], se3 = csr[i + 3];
    float2 r0 = hb[(size_t)se0.x * 32 + lane];
    float2 r1 = hb[(size_t)se1.x * 32 + lane];
    float2 r2 = hb[(size_t)se2.x * 32 + lane];
    float2 r3 = hb[(size_t)se3.x * 32 + lane];
    float p0 = wexp[se0.y] * inv, p1 = wexp[se1.y] * inv;
    float p2 = wexp[se2.y] * inv, p3 = wexp[se3.y] * inv;
    float2 f;
    f = __half22float2(*(__half2*)&r0.x); a0 = fmaf(p0, f.x, a0); a1 = fmaf(p0, f.y, a1);
    f = __half22float2(*(__half2*)&r0.y); a2 = fmaf(p0, f.x, a2); a3 = fmaf(p0, f.y, a3);
    f = __half22float2(*(__half2*)&r1.x); a0 = fmaf(p1, f.x, a0); a1 = fmaf(p1, f.y, a1);
    f = __half22float2(*(__half2*)&r1.y); a2 = fmaf(p1, f.x, a2); a3 = fmaf(p1, f.y, a3);
    f = __half22float2(*(__half2*)&r2.x); a0 = fmaf(p2, f.x, a0); a1 = fmaf(p2, f.y, a1);
    f = __half22float2(*(__half2*)&r2.y); a2 = fmaf(p2, f.x, a2); a3 = fmaf(p2, f.y, a3);
    f = __half22float2(*(__half2*)&r3.x); a0 = fmaf(p3, f.x, a0); a1 = fmaf(p3, f.y, a1);
    f = __half22float2(*(__half2*)&r3.y); a2 = fmaf(p3, f.x, a2); a3 = fmaf(p3, f.y, a3);
  }
  for (; i < s1; i++){
    int2 se = csr[i];
    float2 r = hb[(size_t)se.x * 32 + lane];
    float p = wexp[se.y] * inv;
    float2 f;
    f = __half22float2(*(__half2*)&r.x); a0 = fmaf(p, f.x, a0); a1 = fmaf(p, f.y, a1);
    f = __half22float2(*(__half2*)&r.y); a2 = fmaf(p, f.x, a2); a3 = fmaf(p, f.y, a3);
  }

  float4 b4 = *(const float4*)&bias[lane * 4];
  float v0 = a0 + b4.x; v0 = v0 > 0.f ? v0 : 0.f;
  float v1 = a1 + b4.y; v1 = v1 > 0.f ? v1 : 0.f;
  float v2 = a2 + b4.z; v2 = v2 > 0.f ? v2 : 0.f;
  float v3 = a3 + b4.w; v3 = v3 > 0.f ? v3 : 0.f;
  if (hnext){
    float2 pk;
    __half2* p2h = (__half2*)&pk;
    p2h[0] = __floats2half2_rn(v0, v1);
    p2h[1] = __floats2half2_rn(v2, v3);
    *(float2*)&hnext[(size_t)n * HD + lane * 4] = pk;
  }
  *(float4*)&out[(size_t)n * OUTW + outoff + lane * 4] = make_float4(v0, v1, v2, v3);
}

// ---------- launch ----------

extern "C" void kernel_launch(void* const* d_in, const int* in_sizes, int n_in,
                              void* d_out, int out_size, void* d_ws, size_t ws_size,
                              hipStream_t stream){
  (void)in_sizes; (void)n_in; (void)out_size; (void)ws_size;
  const float* x    = (const float*)d_in[0];
  const void*  ei   = d_in[1];
  const float* eatt = (const float*)d_in[2];
  const float* W0   = (const float*)d_in[3];
  const float* as0  = (const float*)d_in[4];
  const float* ad0  = (const float*)d_in[5];
  const float* We0  = (const float*)d_in[6];
  const float* ae0  = (const float*)d_in[7];
  const float* b0   = (const float*)d_in[8];
  const float* W1   = (const float*)d_in[9];
  const float* as1  = (const float*)d_in[10];
  const float* ad1  = (const float*)d_in[11];
  const float* We1  = (const float*)d_in[12];
  const float* ae1  = (const float*)d_in[13];
  const float* b1   = (const float*)d_in[14];
  float* out = (float*)d_out;

  char* ws = (char*)d_ws;
  size_t off = 0;
  auto alloc = [&](size_t bytes) -> void* {
    void* p = ws + off;
    off += (bytes + 255) & ~(size_t)255;
    return p;
  };
  __half*   hp_h     = (__half*)  alloc((size_t)N_NODES * HD * 2);
  __half*   h1       = (__half*)  alloc((size_t)N_NODES * HD * 2);
  float*    ssrc     = (float*)   alloc((size_t)N_NODES * 4);
  float*    sdst     = (float*)   alloc((size_t)N_NODES * 4);
  float*    wexp     = (float*)   alloc((size_t)TOT * 4);
  float*    denom    = (float*)   alloc((size_t)N_NODES * 2 * 4);  // two layers
  int*      deg      = (int*)     alloc((size_t)N_NODES * 4);
  int*      rowstart = (int*)     alloc((size_t)N_NODES * 4);
  int*      rowcur   = (int*)     alloc((size_t)N_NODES * 4);
  int*      src32    = (int*)     alloc((size_t)N_EDGES * 4);
  int*      dst32    = (int*)     alloc((size_t)N_EDGES * 4);
  int2*     csr      = (int2*)    alloc((size_t)TOT * 8);
  int*      chunksums= (int*)     alloc(64 * 4);
  float*    scal     = (float*)   alloc(64 * 4);   // [0]=sum(edge_attr) [1]=ce0 [2]=ce1
  int*      flag     = (int*)     alloc(64);
  float*    denom0   = denom;
  float*    denom1   = denom + N_NODES;

  hipMemsetAsync(deg,    0, (size_t)N_NODES * 4, stream);
  hipMemsetAsync(denom,  0, (size_t)N_NODES * 2 * 4, stream);
  hipMemsetAsync(scal,   0, 64 * 4, stream);

  const int EB = (TOT + 255) / 256;
  const int nchunks = (N_NODES + 1023) / 1024;

  detect_idx_kernel<<<1, 1, 0, stream>>>(ei, flag);
  mean_kernel<<<256, 256, 0, stream>>>(eatt, scal);
  ce_kernel<<<1, 128, 0, stream>>>(We0, ae0, We1, ae1, scal);
  degconv_kernel<<<EB, 256, 0, stream>>>(ei, flag, deg, src32, dst32);
  scan_chunk_kernel<<<nchunks, 256, 0, stream>>>(deg, rowstart, chunksums);
  scan_top_kernel<<<1, 64, 0, stream>>>(chunksums, nchunks);
  add_off_kernel<<<nchunks, 256, 0, stream>>>(rowstart, rowcur, chunksums);
  fill_kernel<<<EB, 256, 0, stream>>>(src32, dst32, rowcur, csr);
  copyx_kernel<<<(N_NODES * HD / 4 + 255) / 256, 256, 0, stream>>>(x, out);

  const int GB = (N_NODES + BM - 1) / BM;   // 782
  const int AB = (N_NODES + 7) / 8;         // agg blocks (8 nodes per block)

  // layer 0
  gemm_kernel<float><<<GB, 128, 0, stream>>>(x, W0, hp_h);
  score_kernel<<<(N_NODES + 3) / 4, 256, 0, stream>>>(hp_h, as0, ad0, ssrc, sdst);
  edge_kernel<<<EB, 256, 0, stream>>>(src32, dst32, eatt, ssrc, sdst, scal, 0, wexp, denom0);
  agg_kernel<<<AB, 256, 0, stream>>>(rowstart, csr, wexp, denom0, hp_h, b0, h1, out, 128);

  // layer 1
  gemm_kernel<__half><<<GB, 128, 0, stream>>>(h1, W1, hp_h);
  score_kernel<<<(N_NODES + 3) / 4, 256, 0, stream>>>(hp_h, as1, ad1, ssrc, sdst);
  edge_kernel<<<EB, 256, 0, stream>>>(src32, dst32, eatt, ssrc, sdst, scal, 1, wexp, denom1);
  agg_kernel<<<AB, 256, 0, stream>>>(rowstart, csr, wexp, denom1, hp_h, b1, nullptr, out, 256);
}

// Round 6
// 377.352 us; speedup vs baseline: 2.1951x; 1.1844x over previous
//
#include <hip/hip_runtime.h>
#include <hip/hip_fp16.h>
#include <math.h>
#include <type_traits>

#define N_NODES 50000
#define N_EDGES 600000
#define TOT (N_EDGES + N_NODES)   // 650000 edges incl. self-loops
#define HD 128
#define OUTW 384
#define NEG_SLOPE 0.2f

// ---------- helpers ----------

// edge_index may arrive as int32 or int64; runtime-detected flag (uniform branch)
static __device__ __forceinline__ int load_edge(const void* ei, int is64, long long off){
  return is64 ? (int)((const long long*)ei)[off] : ((const int*)ei)[off];
}

// ---------- one-time per-launch kernels ----------

// fused: int64-layout detect + ce0/ce1 = dot(We, att_e) + scal[0] zero-init
__global__ __launch_bounds__(128) void prep_kernel(const void* ei, int* flag,
                                                   const float* __restrict__ We0, const float* __restrict__ ae0,
                                                   const float* __restrict__ We1, const float* __restrict__ ae1,
                                                   float* scal){
  __shared__ float buf[128];
  __shared__ int okbuf;
  int t = threadIdx.x;
  if (t == 0) okbuf = 1;
  __syncthreads();
  if (t < 64){
    long long v = ((const long long*)ei)[t];
    if (v < 0 || v >= N_NODES) atomicAnd(&okbuf, 0);
  }
  buf[t] = We0[t] * ae0[t];
  __syncthreads();
  for (int off = 64; off > 0; off >>= 1){ if (t < off) buf[t] += buf[t + off]; __syncthreads(); }
  if (t == 0) scal[1] = buf[0];
  __syncthreads();
  buf[t] = We1[t] * ae1[t];
  __syncthreads();
  for (int off = 64; off > 0; off >>= 1){ if (t < off) buf[t] += buf[t + off]; __syncthreads(); }
  if (t == 0){ scal[2] = buf[0]; scal[0] = 0.f; *flag = okbuf; }
}

__global__ __launch_bounds__(256) void mean_kernel(const float* __restrict__ ea, float* meansum){
  int tid = blockIdx.x * blockDim.x + threadIdx.x;
  float s = 0.f;
  for (int i = tid; i < N_EDGES; i += gridDim.x * blockDim.x) s += ea[i];
  for (int off = 32; off > 0; off >>= 1) s += __shfl_down(s, off, 64);
  __shared__ float ws[4];
  int lane = threadIdx.x & 63, w = threadIdx.x >> 6;
  if (lane == 0) ws[w] = s;
  __syncthreads();
  if (threadIdx.x == 0){
    atomicAdd(meansum, ws[0] + ws[1] + ws[2] + ws[3]);
  }
}

// degree count + one-time int64 -> int32 src/dst decode (coalesced write)
__global__ __launch_bounds__(256) void degconv_kernel(const void* ei, const int* flag, int* deg,
                                                      int* __restrict__ src32, int* __restrict__ dst32){
  int e = blockIdx.x * 256 + threadIdx.x;
  if (e >= TOT) return;
  int is64 = *flag;
  int d;
  if (e < N_EDGES){
    int s = load_edge(ei, is64, e);
    d = load_edge(ei, is64, (long long)N_EDGES + e);
    src32[e] = s;
    dst32[e] = d;
  } else {
    d = e - N_EDGES;
  }
  atomicAdd(&deg[d], 1);
}

// exclusive scan of deg[0..N) -> rowstart, 1024-element chunks
__global__ __launch_bounds__(256) void scan_chunk_kernel(const int* __restrict__ deg,
                                                         int* __restrict__ rowstart,
                                                         int* __restrict__ chunksums){
  __shared__ int sums[256];
  int t = threadIdx.x;
  int base = blockIdx.x * 1024 + t * 4;
  int v[4];
  #pragma unroll
  for (int i = 0; i < 4; i++) v[i] = (base + i < N_NODES) ? deg[base + i] : 0;
  int tsum = v[0] + v[1] + v[2] + v[3];
  sums[t] = tsum;
  __syncthreads();
  for (int off = 1; off < 256; off <<= 1){
    int add = (t >= off) ? sums[t - off] : 0;
    __syncthreads();
    sums[t] += add;
    __syncthreads();
  }
  int run = sums[t] - tsum;
  #pragma unroll
  for (int i = 0; i < 4; i++){
    if (base + i < N_NODES) rowstart[base + i] = run;
    run += v[i];
  }
  if (t == 255) chunksums[blockIdx.x] = sums[255];
}

__global__ void scan_top_kernel(int* chunksums, int nchunks){
  if (threadIdx.x == 0 && blockIdx.x == 0){
    int run = 0;
    for (int c = 0; c < nchunks; c++){ int v = chunksums[c]; chunksums[c] = run; run += v; }
  }
}

// add chunk offsets; also emit a second copy (rowcur) used as the fill cursor
__global__ __launch_bounds__(256) void add_off_kernel(int* rowstart, int* rowcur, const int* chunksums){
  int base = blockIdx.x * 1024 + threadIdx.x * 4;
  int off = chunksums[blockIdx.x];
  #pragma unroll
  for (int i = 0; i < 4; i++){
    if (base + i < N_NODES){
      int v = rowstart[base + i] + off;
      rowstart[base + i] = v;
      rowcur[base + i] = v;
    }
  }
}

// bucket fill: one packed int2 (src, eid) scattered store per edge
__global__ __launch_bounds__(256) void fill_kernel(const int* __restrict__ src32,
                                                   const int* __restrict__ dst32,
                                                   int* rowcur, int2* __restrict__ csr){
  int e = blockIdx.x * 256 + threadIdx.x;
  if (e >= TOT) return;
  int s, d;
  if (e < N_EDGES){
    s = src32[e];
    d = dst32[e];
  } else {
    s = d = e - N_EDGES;
  }
  int pos = atomicAdd(&rowcur[d], 1);
  csr[pos] = make_int2(s, e);
}

// ---------- per-layer kernels ----------

// Register-tiled GEMM: hp_h[M,128] = fp16( hin[M,128] @ W[128,128]^T ), input fp32 or fp16.
// Fused epilogue: ssrc/sdst per-row dots with att_src/att_dst (16-lane shfl reduce).
// Layer 0 also streams x into out[:, 0:128] during A-staging (outx != nullptr).
// BM=64 rows/block, BN=128, BK=16, 128 threads, 8x8 per thread.
#define BM 64
#define BK 16

struct __align__(16) H8 { __half2 a, b, c, d; };

template <typename T>
__global__ __launch_bounds__(128, 3) void gemm_kernel(const T* __restrict__ hin,
                                                      const float* __restrict__ W,
                                                      __half* __restrict__ hp_h,
                                                      const float* __restrict__ as_,
                                                      const float* __restrict__ ad_,
                                                      float* __restrict__ ssrc,
                                                      float* __restrict__ sdst,
                                                      float* __restrict__ outx){
  __shared__ float As[BK][BM + 4];    // 16 x 68 floats = 4.25 KB
  __shared__ float Ws[BK][HD + 4];    // 16 x 132 floats = 8.25 KB
  int t  = threadIdx.x;
  int tx = t & 15;          // col group: cols tx*8 .. +7
  int ty = t >> 4;          // row group: rows ty*8 .. +7
  int rb = blockIdx.x * BM;

  float acc[8][8];
  #pragma unroll
  for (int i = 0; i < 8; i++)
    #pragma unroll
    for (int j = 0; j < 8; j++) acc[i][j] = 0.f;

  for (int kb = 0; kb < HD; kb += BK){
    #pragma unroll
    for (int p = 0; p < 2; p++){
      int idx = t + p * 128;          // 0..255
      int row = idx >> 2;             // 0..63
      int kq  = (idx & 3) << 2;       // 0,4,8,12
      int gr  = rb + row;
      if (gr > N_NODES - 1) gr = N_NODES - 1;   // clamp (tail rows never stored)
      float vx, vy, vz, vw;
      if constexpr (std::is_same<T, float>::value){
        float4 v = *(const float4*)&hin[(size_t)gr * HD + kb + kq];
        vx = v.x; vy = v.y; vz = v.z; vw = v.w;
        if (outx) *(float4*)&outx[(size_t)gr * OUTW + kb + kq] = v;   // JK-cat slot 0
      } else {
        float2 raw = *(const float2*)&hin[(size_t)gr * HD + kb + kq];  // 4 halves
        const __half2* h2 = (const __half2*)&raw;
        float2 f0 = __half22float2(h2[0]);
        float2 f1 = __half22float2(h2[1]);
        vx = f0.x; vy = f0.y; vz = f1.x; vw = f1.y;
      }
      As[kq + 0][row] = vx; As[kq + 1][row] = vy;
      As[kq + 2][row] = vz; As[kq + 3][row] = vw;
    }
    #pragma unroll
    for (int p = 0; p < 4; p++){
      int idx = t + p * 128;          // 0..511
      int n   = idx >> 2;             // 0..127
      int kq  = (idx & 3) << 2;
      float4 v = *(const float4*)&W[(size_t)n * HD + kb + kq];
      Ws[kq + 0][n] = v.x; Ws[kq + 1][n] = v.y;
      Ws[kq + 2][n] = v.z; Ws[kq + 3][n] = v.w;
    }
    __syncthreads();
    #pragma unroll
    for (int k = 0; k < BK; k++){
      float a[8], w[8];
      *(float4*)&a[0] = *(const float4*)&As[k][ty * 8];
      *(float4*)&a[4] = *(const float4*)&As[k][ty * 8 + 4];
      *(float4*)&w[0] = *(const float4*)&Ws[k][tx * 8];
      *(float4*)&w[4] = *(const float4*)&Ws[k][tx * 8 + 4];
      #pragma unroll
      for (int i = 0; i < 8; i++)
        #pragma unroll
        for (int j = 0; j < 8; j++)
          acc[i][j] = fmaf(a[i], w[j], acc[i][j]);
    }
    __syncthreads();
  }

  // store hp (fp16)
  #pragma unroll
  for (int i = 0; i < 8; i++){
    int r = rb + ty * 8 + i;
    if (r < N_NODES){
      H8 pk;
      pk.a = __floats2half2_rn(acc[i][0], acc[i][1]);
      pk.b = __floats2half2_rn(acc[i][2], acc[i][3]);
      pk.c = __floats2half2_rn(acc[i][4], acc[i][5]);
      pk.d = __floats2half2_rn(acc[i][6], acc[i][7]);
      *(H8*)&hp_h[(size_t)r * HD + tx * 8] = pk;
    }
  }

  // fused score: per-row dot with att_src/att_dst, reduce over the 16 col-groups
  float as_v[8], ad_v[8];
  #pragma unroll
  for (int j = 0; j < 8; j++){ as_v[j] = as_[tx * 8 + j]; ad_v[j] = ad_[tx * 8 + j]; }
  #pragma unroll
  for (int i = 0; i < 8; i++){
    float ps = 0.f, pd = 0.f;
    #pragma unroll
    for (int j = 0; j < 8; j++){
      ps = fmaf(acc[i][j], as_v[j], ps);
      pd = fmaf(acc[i][j], ad_v[j], pd);
    }
    #pragma unroll
    for (int off = 8; off > 0; off >>= 1){
      ps += __shfl_down(ps, off, 16);
      pd += __shfl_down(pd, off, 16);
    }
    int r = rb + ty * 8 + i;
    if (tx == 0 && r < N_NODES){ ssrc[r] = ps; sdst[r] = pd; }
  }
}

// node-parallel attention: 1 thread per dst node; computes exp-weights in CSR
// order (wp[i], coalesced for agg) and the per-node 1/denominator (no atomics).
__global__ __launch_bounds__(256) void attn_kernel(const int* __restrict__ rowstart,
                                                   const int2* __restrict__ csr,
                                                   const float* __restrict__ eattr,
                                                   const float* __restrict__ ssrc,
                                                   const float* __restrict__ sdst,
                                                   const float* __restrict__ scal, int which,
                                                   float* __restrict__ wp,
                                                   float* __restrict__ pinv){
  int n = blockIdx.x * 256 + threadIdx.x;
  if (n >= N_NODES) return;
  int s0 = rowstart[n];
  int s1 = (n + 1 < N_NODES) ? rowstart[n + 1] : TOT;
  float sd = sdst[n];
  float ce = scal[1 + which];
  float mean_ea = scal[0] * (1.0f / (float)N_EDGES);
  float sum = 0.f;
  for (int i = s0; i < s1; i++){
    int2 se = csr[i];
    float eav = (se.y < N_EDGES) ? eattr[se.y] : mean_ea;
    float a = ssrc[se.x] + sd + eav * ce;
    a = (a >= 0.f) ? a : NEG_SLOPE * a;   // leaky_relu
    float w = expf(a);
    wp[i] = w;
    sum += w;
  }
  pinv[n] = 1.0f / (sum + 1e-16f);
}

// aggregation: 32 lanes per dst node (2 nodes per wave, 8 per 256-block),
// lane covers 4 cols (half4 = 8B), edge loop unrolled x4; weights read
// sequentially (broadcast), 1/denom folded into the epilogue.
__global__ __launch_bounds__(256) void agg_kernel(const int* __restrict__ rowstart,
                                                  const int2* __restrict__ csr,
                                                  const float* __restrict__ wp,
                                                  const float* __restrict__ pinv,
                                                  const __half* __restrict__ hp_h,
                                                  const float* __restrict__ bias,
                                                  __half* __restrict__ hnext,
                                                  float* __restrict__ out, int outoff){
  int sub  = threadIdx.x >> 5;     // 0..7 : node slot within block
  int lane = threadIdx.x & 31;     // covers cols 4*lane .. +3
  int n = blockIdx.x * 8 + sub;
  if (n >= N_NODES) return;
  int s0 = rowstart[n];
  int s1 = (n + 1 < N_NODES) ? rowstart[n + 1] : TOT;
  const float2* hb = (const float2*)hp_h;   // one float2 = 4 halves; row stride = 32

  float a0 = 0.f, a1 = 0.f, a2 = 0.f, a3 = 0.f;
  int i = s0;
  for (; i + 4 <= s1; i += 4){
    int2 se0 = csr[i],     se1 = csr[i + 1];
    int2 se2 = csr[i + 2], se3 = csr[i + 3];
    float p0 = wp[i],     p1 = wp[i + 1];
    float p2 = wp[i + 2], p3 = wp[i + 3];
    float2 r0 = hb[(size_t)se0.x * 32 + lane];
    float2 r1 = hb[(size_t)se1.x * 32 + lane];
    float2 r2 = hb[(size_t)se2.x * 32 + lane];
    float2 r3 = hb[(size_t)se3.x * 32 + lane];
    float2 f;
    f = __half22float2(*(__half2*)&r0.x); a0 = fmaf(p0, f.x, a0); a1 = fmaf(p0, f.y, a1);
    f = __half22float2(*(__half2*)&r0.y); a2 = fmaf(p0, f.x, a2); a3 = fmaf(p0, f.y, a3);
    f = __half22float2(*(__half2*)&r1.x); a0 = fmaf(p1, f.x, a0); a1 = fmaf(p1, f.y, a1);
    f = __half22float2(*(__half2*)&r1.y); a2 = fmaf(p1, f.x, a2); a3 = fmaf(p1, f.y, a3);
    f = __half22float2(*(__half2*)&r2.x); a0 = fmaf(p2, f.x, a0); a1 = fmaf(p2, f.y, a1);
    f = __half22float2(*(__half2*)&r2.y); a2 = fmaf(p2, f.x, a2); a3 = fmaf(p2, f.y, a3);
    f = __half22float2(*(__half2*)&r3.x); a0 = fmaf(p3, f.x, a0); a1 = fmaf(p3, f.y, a1);
    f = __half22float2(*(__half2*)&r3.y); a2 = fmaf(p3, f.x, a2); a3 = fmaf(p3, f.y, a3);
  }
  for (; i < s1; i++){
    int2 se = csr[i];
    float p = wp[i];
    float2 r = hb[(size_t)se.x * 32 + lane];
    float2 f;
    f = __half22float2(*(__half2*)&r.x); a0 = fmaf(p, f.x, a0); a1 = fmaf(p, f.y, a1);
    f = __half22float2(*(__half2*)&r.y); a2 = fmaf(p, f.x, a2); a3 = fmaf(p, f.y, a3);
  }

  float inv = pinv[n];
  float4 b4 = *(const float4*)&bias[lane * 4];
  float v0 = fmaf(a0, inv, b4.x); v0 = v0 > 0.f ? v0 : 0.f;
  float v1 = fmaf(a1, inv, b4.y); v1 = v1 > 0.f ? v1 : 0.f;
  float v2 = fmaf(a2, inv, b4.z); v2 = v2 > 0.f ? v2 : 0.f;
  float v3 = fmaf(a3, inv, b4.w); v3 = v3 > 0.f ? v3 : 0.f;
  if (hnext){
    float2 pk;
    __half2* p2h = (__half2*)&pk;
    p2h[0] = __floats2half2_rn(v0, v1);
    p2h[1] = __floats2half2_rn(v2, v3);
    *(float2*)&hnext[(size_t)n * HD + lane * 4] = pk;
  }
  *(float4*)&out[(size_t)n * OUTW + outoff + lane * 4] = make_float4(v0, v1, v2, v3);
}

// ---------- launch ----------

extern "C" void kernel_launch(void* const* d_in, const int* in_sizes, int n_in,
                              void* d_out, int out_size, void* d_ws, size_t ws_size,
                              hipStream_t stream){
  (void)in_sizes; (void)n_in; (void)out_size; (void)ws_size;
  const float* x    = (const float*)d_in[0];
  const void*  ei   = d_in[1];
  const float* eatt = (const float*)d_in[2];
  const float* W0   = (const float*)d_in[3];
  const float* as0  = (const float*)d_in[4];
  const float* ad0  = (const float*)d_in[5];
  const float* We0  = (const float*)d_in[6];
  const float* ae0  = (const float*)d_in[7];
  const float* b0   = (const float*)d_in[8];
  const float* W1   = (const float*)d_in[9];
  const float* as1  = (const float*)d_in[10];
  const float* ad1  = (const float*)d_in[11];
  const float* We1  = (const float*)d_in[12];
  const float* ae1  = (const float*)d_in[13];
  const float* b1   = (const float*)d_in[14];
  float* out = (float*)d_out;

  char* ws = (char*)d_ws;
  size_t off = 0;
  auto alloc = [&](size_t bytes) -> void* {
    void* p = ws + off;
    off += (bytes + 255) & ~(size_t)255;
    return p;
  };
  __half*   hp_h     = (__half*)  alloc((size_t)N_NODES * HD * 2);
  __half*   h1       = (__half*)  alloc((size_t)N_NODES * HD * 2);
  float*    ssrc     = (float*)   alloc((size_t)N_NODES * 4);
  float*    sdst     = (float*)   alloc((size_t)N_NODES * 4);
  float*    wp       = (float*)   alloc((size_t)TOT * 4);
  float*    pinv     = (float*)   alloc((size_t)N_NODES * 4);
  int*      deg      = (int*)     alloc((size_t)N_NODES * 4);
  int*      rowstart = (int*)     alloc((size_t)N_NODES * 4);
  int*      rowcur   = (int*)     alloc((size_t)N_NODES * 4);
  int*      src32    = (int*)     alloc((size_t)N_EDGES * 4);
  int*      dst32    = (int*)     alloc((size_t)N_EDGES * 4);
  int2*     csr      = (int2*)    alloc((size_t)TOT * 8);
  int*      chunksums= (int*)     alloc(64 * 4);
  float*    scal     = (float*)   alloc(64 * 4);   // [0]=sum(edge_attr) [1]=ce0 [2]=ce1
  int*      flag     = (int*)     alloc(64);

  hipMemsetAsync(deg, 0, (size_t)N_NODES * 4, stream);

  const int EB = (TOT + 255) / 256;
  const int nchunks = (N_NODES + 1023) / 1024;
  const int NB = (N_NODES + 255) / 256;

  prep_kernel<<<1, 128, 0, stream>>>(ei, flag, We0, ae0, We1, ae1, scal);
  mean_kernel<<<256, 256, 0, stream>>>(eatt, scal);
  degconv_kernel<<<EB, 256, 0, stream>>>(ei, flag, deg, src32, dst32);
  scan_chunk_kernel<<<nchunks, 256, 0, stream>>>(deg, rowstart, chunksums);
  scan_top_kernel<<<1, 64, 0, stream>>>(chunksums, nchunks);
  add_off_kernel<<<nchunks, 256, 0, stream>>>(rowstart, rowcur, chunksums);
  fill_kernel<<<EB, 256, 0, stream>>>(src32, dst32, rowcur, csr);

  const int GB = (N_NODES + BM - 1) / BM;   // 782
  const int AB = (N_NODES + 7) / 8;         // agg blocks (8 nodes per block)

  // layer 0 (gemm also streams x into out[:,0:128])
  gemm_kernel<float><<<GB, 128, 0, stream>>>(x, W0, hp_h, as0, ad0, ssrc, sdst, out);
  attn_kernel<<<NB, 256, 0, stream>>>(rowstart, csr, eatt, ssrc, sdst, scal, 0, wp, pinv);
  agg_kernel<<<AB, 256, 0, stream>>>(rowstart, csr, wp, pinv, hp_h, b0, h1, out, 128);

  // layer 1
  gemm_kernel<__half><<<GB, 128, 0, stream>>>(h1, W1, hp_h, as1, ad1, ssrc, sdst, nullptr);
  attn_kernel<<<NB, 256, 0, stream>>>(rowstart, csr, eatt, ssrc, sdst, scal, 1, wp, pinv);
  agg_kernel<<<AB, 256, 0, stream>>>(rowstart, csr, wp, pinv, hp_h, b1, nullptr, out, 256);
}

// Round 7
// 374.884 us; speedup vs baseline: 2.2095x; 1.0066x over previous
//
#include <hip/hip_runtime.h>
#include <hip/hip_fp16.h>
#include <math.h>
#include <type_traits>

#define N_NODES 50000
#define N_EDGES 600000
#define TOT (N_EDGES + N_NODES)   // 650000 edges incl. self-loops
#define HD 128
#define OUTW 384
#define NEG_SLOPE 0.2f

// ---------- helpers ----------

typedef _Float16 h2_t __attribute__((ext_vector_type(2)));

static __device__ __forceinline__ float fdot2f(h2_t a, h2_t b, float c){
#if __has_builtin(__builtin_amdgcn_fdot2)
  return __builtin_amdgcn_fdot2(a, b, c, false);
#else
  return fmaf((float)a[0], (float)b[0], fmaf((float)a[1], (float)b[1], c));
#endif
}

// edge_index may arrive as int32 or int64; runtime-detected flag (uniform branch)
static __device__ __forceinline__ int load_edge(const void* ei, int is64, long long off){
  return is64 ? (int)((const long long*)ei)[off] : ((const int*)ei)[off];
}

// ---------- one-time per-launch kernels ----------

// fused: int64-layout detect + ce0/ce1 = dot(We, att_e) + scal[0] zero-init
__global__ __launch_bounds__(128) void prep_kernel(const void* ei, int* flag,
                                                   const float* __restrict__ We0, const float* __restrict__ ae0,
                                                   const float* __restrict__ We1, const float* __restrict__ ae1,
                                                   float* scal){
  __shared__ float buf[128];
  __shared__ int okbuf;
  int t = threadIdx.x;
  if (t == 0) okbuf = 1;
  __syncthreads();
  if (t < 64){
    long long v = ((const long long*)ei)[t];
    if (v < 0 || v >= N_NODES) atomicAnd(&okbuf, 0);
  }
  buf[t] = We0[t] * ae0[t];
  __syncthreads();
  for (int off = 64; off > 0; off >>= 1){ if (t < off) buf[t] += buf[t + off]; __syncthreads(); }
  if (t == 0) scal[1] = buf[0];
  __syncthreads();
  buf[t] = We1[t] * ae1[t];
  __syncthreads();
  for (int off = 64; off > 0; off >>= 1){ if (t < off) buf[t] += buf[t + off]; __syncthreads(); }
  if (t == 0){ scal[2] = buf[0]; scal[0] = 0.f; *flag = okbuf; }
}

// convert both weight matrices to k-paired fp16 layout: Wt[k2*128 + n] = (W[n][2k2], W[n][2k2+1])
__global__ __launch_bounds__(256) void wconv_kernel(const float* __restrict__ W0, const float* __restrict__ W1,
                                                    __half2* __restrict__ Wt0, __half2* __restrict__ Wt1){
  int e = blockIdx.x * 256 + threadIdx.x;     // 0..16383
  if (e >= 16384) return;
  const float* W = (e < 8192) ? W0 : W1;
  __half2* Wt = (e < 8192) ? Wt0 : Wt1;
  int i = e & 8191;
  int n = i & 127, k2 = i >> 7;
  float a = W[n * HD + 2 * k2];
  float b = W[n * HD + 2 * k2 + 1];
  Wt[k2 * 128 + n] = __floats2half2_rn(a, b);
}

__global__ __launch_bounds__(256) void mean_kernel(const float* __restrict__ ea, float* meansum){
  int tid = blockIdx.x * blockDim.x + threadIdx.x;
  float s = 0.f;
  for (int i = tid; i < N_EDGES; i += gridDim.x * blockDim.x) s += ea[i];
  for (int off = 32; off > 0; off >>= 1) s += __shfl_down(s, off, 64);
  __shared__ float ws[4];
  int lane = threadIdx.x & 63, w = threadIdx.x >> 6;
  if (lane == 0) ws[w] = s;
  __syncthreads();
  if (threadIdx.x == 0){
    atomicAdd(meansum, ws[0] + ws[1] + ws[2] + ws[3]);
  }
}

// degree count + one-time int64 -> int32 src/dst decode (coalesced write)
__global__ __launch_bounds__(256) void degconv_kernel(const void* ei, const int* flag, int* deg,
                                                      int* __restrict__ src32, int* __restrict__ dst32){
  int e = blockIdx.x * 256 + threadIdx.x;
  if (e >= TOT) return;
  int is64 = *flag;
  int d;
  if (e < N_EDGES){
    int s = load_edge(ei, is64, e);
    d = load_edge(ei, is64, (long long)N_EDGES + e);
    src32[e] = s;
    dst32[e] = d;
  } else {
    d = e - N_EDGES;
  }
  atomicAdd(&deg[d], 1);
}

// exclusive scan of deg[0..N) -> rowstart, 1024-element chunks
__global__ __launch_bounds__(256) void scan_chunk_kernel(const int* __restrict__ deg,
                                                         int* __restrict__ rowstart,
                                                         int* __restrict__ chunksums){
  __shared__ int sums[256];
  int t = threadIdx.x;
  int base = blockIdx.x * 1024 + t * 4;
  int v[4];
  #pragma unroll
  for (int i = 0; i < 4; i++) v[i] = (base + i < N_NODES) ? deg[base + i] : 0;
  int tsum = v[0] + v[1] + v[2] + v[3];
  sums[t] = tsum;
  __syncthreads();
  for (int off = 1; off < 256; off <<= 1){
    int add = (t >= off) ? sums[t - off] : 0;
    __syncthreads();
    sums[t] += add;
    __syncthreads();
  }
  int run = sums[t] - tsum;
  #pragma unroll
  for (int i = 0; i < 4; i++){
    if (base + i < N_NODES) rowstart[base + i] = run;
    run += v[i];
  }
  if (t == 255) chunksums[blockIdx.x] = sums[255];
}

__global__ void scan_top_kernel(int* chunksums, int nchunks){
  if (threadIdx.x == 0 && blockIdx.x == 0){
    int run = 0;
    for (int c = 0; c < nchunks; c++){ int v = chunksums[c]; chunksums[c] = run; run += v; }
  }
}

// add chunk offsets; also emit a second copy (rowcur) used as the fill cursor
__global__ __launch_bounds__(256) void add_off_kernel(int* rowstart, int* rowcur, const int* chunksums){
  int base = blockIdx.x * 1024 + threadIdx.x * 4;
  int off = chunksums[blockIdx.x];
  #pragma unroll
  for (int i = 0; i < 4; i++){
    if (base + i < N_NODES){
      int v = rowstart[base + i] + off;
      rowstart[base + i] = v;
      rowcur[base + i] = v;
    }
  }
}

// bucket fill: one packed int2 (src, eid) scattered store per edge
__global__ __launch_bounds__(256) void fill_kernel(const int* __restrict__ src32,
                                                   const int* __restrict__ dst32,
                                                   int* rowcur, int2* __restrict__ csr){
  int e = blockIdx.x * 256 + threadIdx.x;
  if (e >= TOT) return;
  int s, d;
  if (e < N_EDGES){
    s = src32[e];
    d = dst32[e];
  } else {
    s = d = e - N_EDGES;
  }
  int pos = atomicAdd(&rowcur[d], 1);
  csr[pos] = make_int2(s, e);
}

// ---------- per-layer kernels ----------

// fdot2 GEMM: hp_h[M,128] = fp16( hin[M,128] @ W^T ), W pre-packed fp16 (Wt[k2][n]).
// BM=64 rows/block, 128 threads, 8 rows x 8 cols per thread (cols tx*4..+3 and 64+tx*4..+3).
// A and W staged into LDS ONCE (single barrier), then 64 k2-steps of 4 b128 + 64 v_dot2_f32_f16.
// Fused epilogue: ssrc/sdst row dots; layer 0 streams x into out[:,0:128].
#define BM 64
#define AST 68   // As2 row stride in half2 (pad keeps staging writes off a single bank)

template <typename T>
__global__ __launch_bounds__(128, 3) void gemm_kernel(const T* __restrict__ hin,
                                                      const __half2* __restrict__ Wt,
                                                      __half* __restrict__ hp_h,
                                                      const float* __restrict__ as_,
                                                      const float* __restrict__ ad_,
                                                      float* __restrict__ ssrc,
                                                      float* __restrict__ sdst,
                                                      float* __restrict__ outx){
  __shared__ __half2 As2[64 * AST];    // [k2][m]  17408 B
  __shared__ __half2 Wh2[64 * 128];    // [k2][n]  32768 B
  int t  = threadIdx.x;
  int tx = t & 15;
  int ty = t >> 4;                     // 0..7 -> rows ty*8..+7
  int rb = blockIdx.x * BM;

  // stage W: straight 32KB copy (coalesced, conflict-free)
  {
    const float4* src = (const float4*)Wt;
    float4* dst = (float4*)Wh2;
    #pragma unroll
    for (int p = 0; p < 16; p++) dst[t + p * 128] = src[t + p * 128];
  }
  // stage A: full 64x128, packed to half2 [k2][m]
  if constexpr (std::is_same<T, float>::value){
    #pragma unroll
    for (int p = 0; p < 16; p++){
      int idx = t + p * 128;           // 0..2047 float4s
      int row = idx >> 5, c4 = idx & 31;
      int gr = rb + row;
      bool valid = gr < N_NODES;
      int g = valid ? gr : N_NODES - 1;
      float4 v = *(const float4*)&hin[(size_t)g * HD + c4 * 4];
      if (outx && valid) *(float4*)&outx[(size_t)gr * OUTW + c4 * 4] = v;  // JK-cat slot 0
      As2[(2 * c4) * AST + row]     = __floats2half2_rn(v.x, v.y);
      As2[(2 * c4 + 1) * AST + row] = __floats2half2_rn(v.z, v.w);
    }
  } else {
    #pragma unroll
    for (int p = 0; p < 8; p++){
      int idx = t + p * 128;           // 0..1023 float4s (8 halves each)
      int row = idx >> 4, c8 = idx & 15;
      int gr = rb + row; if (gr >= N_NODES) gr = N_NODES - 1;
      float4 v = *(const float4*)&hin[(size_t)gr * HD + c8 * 8];
      __half2* hv = (__half2*)&v;
      #pragma unroll
      for (int q = 0; q < 4; q++) As2[(4 * c8 + q) * AST + row] = hv[q];
    }
  }
  __syncthreads();

  float acc[8][8];
  #pragma unroll
  for (int i = 0; i < 8; i++)
    #pragma unroll
    for (int j = 0; j < 8; j++) acc[i][j] = 0.f;

  #pragma unroll 4
  for (int k2 = 0; k2 < 64; k2++){
    float4 ar0 = *(const float4*)&As2[k2 * AST + ty * 8];        // m = ty*8..+3 (broadcast)
    float4 ar1 = *(const float4*)&As2[k2 * AST + ty * 8 + 4];    // m = +4..+7
    float4 wr0 = *(const float4*)&Wh2[k2 * 128 + tx * 4];        // n = tx*4..+3   (2-way, free)
    float4 wr1 = *(const float4*)&Wh2[k2 * 128 + 64 + tx * 4];   // n = 64+tx*4..+3
    const h2_t* av0 = (const h2_t*)&ar0;
    const h2_t* av1 = (const h2_t*)&ar1;
    const h2_t* wv0 = (const h2_t*)&wr0;
    const h2_t* wv1 = (const h2_t*)&wr1;
    #pragma unroll
    for (int i = 0; i < 8; i++){
      h2_t ai = (i < 4) ? av0[i] : av1[i - 4];
      #pragma unroll
      for (int j = 0; j < 4; j++){
        acc[i][j]     = fdot2f(ai, wv0[j], acc[i][j]);
        acc[i][j + 4] = fdot2f(ai, wv1[j], acc[i][j + 4]);
      }
    }
  }

  // store hp (fp16): two 8B chunks per row (cols tx*4 and 64+tx*4)
  #pragma unroll
  for (int i = 0; i < 8; i++){
    int r = rb + ty * 8 + i;
    if (r < N_NODES){
      float2 s0, s1;
      ((__half2*)&s0)[0] = __floats2half2_rn(acc[i][0], acc[i][1]);
      ((__half2*)&s0)[1] = __floats2half2_rn(acc[i][2], acc[i][3]);
      ((__half2*)&s1)[0] = __floats2half2_rn(acc[i][4], acc[i][5]);
      ((__half2*)&s1)[1] = __floats2half2_rn(acc[i][6], acc[i][7]);
      *(float2*)&hp_h[(size_t)r * HD + tx * 4]      = s0;
      *(float2*)&hp_h[(size_t)r * HD + 64 + tx * 4] = s1;
    }
  }

  // fused score: per-row dot with att_src/att_dst, reduce over the 16 col-groups
  float as_v[8], ad_v[8];
  #pragma unroll
  for (int j = 0; j < 4; j++){
    as_v[j]     = as_[tx * 4 + j];      ad_v[j]     = ad_[tx * 4 + j];
    as_v[j + 4] = as_[64 + tx * 4 + j]; ad_v[j + 4] = ad_[64 + tx * 4 + j];
  }
  #pragma unroll
  for (int i = 0; i < 8; i++){
    float ps = 0.f, pd = 0.f;
    #pragma unroll
    for (int j = 0; j < 8; j++){
      ps = fmaf(acc[i][j], as_v[j], ps);
      pd = fmaf(acc[i][j], ad_v[j], pd);
    }
    #pragma unroll
    for (int off = 8; off > 0; off >>= 1){
      ps += __shfl_down(ps, off, 16);
      pd += __shfl_down(pd, off, 16);
    }
    int r = rb + ty * 8 + i;
    if (tx == 0 && r < N_NODES){ ssrc[r] = ps; sdst[r] = pd; }
  }
}

// node-parallel attention: 1 thread per dst node; computes exp-weights in CSR
// order (wp[i], coalesced for agg) and the per-node 1/denominator (no atomics).
__global__ __launch_bounds__(256) void attn_kernel(const int* __restrict__ rowstart,
                                                   const int2* __restrict__ csr,
                                                   const float* __restrict__ eattr,
                                                   const float* __restrict__ ssrc,
                                                   const float* __restrict__ sdst,
                                                   const float* __restrict__ scal, int which,
                                                   float* __restrict__ wp,
                                                   float* __restrict__ pinv){
  int n = blockIdx.x * 256 + threadIdx.x;
  if (n >= N_NODES) return;
  int s0 = rowstart[n];
  int s1 = (n + 1 < N_NODES) ? rowstart[n + 1] : TOT;
  float sd = sdst[n];
  float ce = scal[1 + which];
  float mean_ea = scal[0] * (1.0f / (float)N_EDGES);
  float sum = 0.f;
  for (int i = s0; i < s1; i++){
    int2 se = csr[i];
    float eav = (se.y < N_EDGES) ? eattr[se.y] : mean_ea;
    float a = ssrc[se.x] + sd + eav * ce;
    a = (a >= 0.f) ? a : NEG_SLOPE * a;   // leaky_relu
    float w = expf(a);
    wp[i] = w;
    sum += w;
  }
  pinv[n] = 1.0f / (sum + 1e-16f);
}

// aggregation: 32 lanes per dst node (2 nodes per wave, 8 per 256-block),
// lane covers 4 cols (half4 = 8B), edge loop unrolled x4; weights read
// sequentially (broadcast), 1/denom folded into the epilogue.
__global__ __launch_bounds__(256) void agg_kernel(const int* __restrict__ rowstart,
                                                  const int2* __restrict__ csr,
                                                  const float* __restrict__ wp,
                                                  const float* __restrict__ pinv,
                                                  const __half* __restrict__ hp_h,
                                                  const float* __restrict__ bias,
                                                  __half* __restrict__ hnext,
                                                  float* __restrict__ out, int outoff){
  int sub  = threadIdx.x >> 5;     // 0..7 : node slot within block
  int lane = threadIdx.x & 31;     // covers cols 4*lane .. +3
  int n = blockIdx.x * 8 + sub;
  if (n >= N_NODES) return;
  int s0 = rowstart[n];
  int s1 = (n + 1 < N_NODES) ? rowstart[n + 1] : TOT;
  const float2* hb = (const float2*)hp_h;   // one float2 = 4 halves; row stride = 32

  float a0 = 0.f, a1 = 0.f, a2 = 0.f, a3 = 0.f;
  int i = s0;
  for (; i + 4 <= s1; i += 4){
    int2 se0 = csr[i],     se1 = csr[i + 1];
    int2 se2 = csr[i + 2], se3 = csr[i + 3];
    float p0 = wp[i],     p1 = wp[i + 1];
    float p2 = wp[i + 2], p3 = wp[i + 3];
    float2 r0 = hb[(size_t)se0.x * 32 + lane];
    float2 r1 = hb[(size_t)se1.x * 32 + lane];
    float2 r2 = hb[(size_t)se2.x * 32 + lane];
    float2 r3 = hb[(size_t)se3.x * 32 + lane];
    float2 f;
    f = __half22float2(*(__half2*)&r0.x); a0 = fmaf(p0, f.x, a0); a1 = fmaf(p0, f.y, a1);
    f = __half22float2(*(__half2*)&r0.y); a2 = fmaf(p0, f.x, a2); a3 = fmaf(p0, f.y, a3);
    f = __half22float2(*(__half2*)&r1.x); a0 = fmaf(p1, f.x, a0); a1 = fmaf(p1, f.y, a1);
    f = __half22float2(*(__half2*)&r1.y); a2 = fmaf(p1, f.x, a2); a3 = fmaf(p1, f.y, a3);
    f = __half22float2(*(__half2*)&r2.x); a0 = fmaf(p2, f.x, a0); a1 = fmaf(p2, f.y, a1);
    f = __half22float2(*(__half2*)&r2.y); a2 = fmaf(p2, f.x, a2); a3 = fmaf(p2, f.y, a3);
    f = __half22float2(*(__half2*)&r3.x); a0 = fmaf(p3, f.x, a0); a1 = fmaf(p3, f.y, a1);
    f = __half22float2(*(__half2*)&r3.y); a2 = fmaf(p3, f.x, a2); a3 = fmaf(p3, f.y, a3);
  }
  for (; i < s1; i++){
    int2 se = csr[i];
    float p = wp[i];
    float2 r = hb[(size_t)se.x * 32 + lane];
    float2 f;
    f = __half22float2(*(__half2*)&r.x); a0 = fmaf(p, f.x, a0); a1 = fmaf(p, f.y, a1);
    f = __half22float2(*(__half2*)&r.y); a2 = fmaf(p, f.x, a2); a3 = fmaf(p, f.y, a3);
  }

  float inv = pinv[n];
  float4 b4 = *(const float4*)&bias[lane * 4];
  float v0 = fmaf(a0, inv, b4.x); v0 = v0 > 0.f ? v0 : 0.f;
  float v1 = fmaf(a1, inv, b4.y); v1 = v1 > 0.f ? v1 : 0.f;
  float v2 = fmaf(a2, inv, b4.z); v2 = v2 > 0.f ? v2 : 0.f;
  float v3 = fmaf(a3, inv, b4.w); v3 = v3 > 0.f ? v3 : 0.f;
  if (hnext){
    float2 pk;
    __half2* p2h = (__half2*)&pk;
    p2h[0] = __floats2half2_rn(v0, v1);
    p2h[1] = __floats2half2_rn(v2, v3);
    *(float2*)&hnext[(size_t)n * HD + lane * 4] = pk;
  }
  *(float4*)&out[(size_t)n * OUTW + outoff + lane * 4] = make_float4(v0, v1, v2, v3);
}

// ---------- launch ----------

extern "C" void kernel_launch(void* const* d_in, const int* in_sizes, int n_in,
                              void* d_out, int out_size, void* d_ws, size_t ws_size,
                              hipStream_t stream){
  (void)in_sizes; (void)n_in; (void)out_size; (void)ws_size;
  const float* x    = (const float*)d_in[0];
  const void*  ei   = d_in[1];
  const float* eatt = (const float*)d_in[2];
  const float* W0   = (const float*)d_in[3];
  const float* as0  = (const float*)d_in[4];
  const float* ad0  = (const float*)d_in[5];
  const float* We0  = (const float*)d_in[6];
  const float* ae0  = (const float*)d_in[7];
  const float* b0   = (const float*)d_in[8];
  const float* W1   = (const float*)d_in[9];
  const float* as1  = (const float*)d_in[10];
  const float* ad1  = (const float*)d_in[11];
  const float* We1  = (const float*)d_in[12];
  const float* ae1  = (const float*)d_in[13];
  const float* b1   = (const float*)d_in[14];
  float* out = (float*)d_out;

  char* ws = (char*)d_ws;
  size_t off = 0;
  auto alloc = [&](size_t bytes) -> void* {
    void* p = ws + off;
    off += (bytes + 255) & ~(size_t)255;
    return p;
  };
  __half*   hp_h     = (__half*)  alloc((size_t)N_NODES * HD * 2);
  __half*   h1       = (__half*)  alloc((size_t)N_NODES * HD * 2);
  float*    ssrc     = (float*)   alloc((size_t)N_NODES * 4);
  float*    sdst     = (float*)   alloc((size_t)N_NODES * 4);
  float*    wp       = (float*)   alloc((size_t)TOT * 4);
  float*    pinv     = (float*)   alloc((size_t)N_NODES * 4);
  int*      deg      = (int*)     alloc((size_t)N_NODES * 4);
  int*      rowstart = (int*)     alloc((size_t)N_NODES * 4);
  int*      rowcur   = (int*)     alloc((size_t)N_NODES * 4);
  int*      src32    = (int*)     alloc((size_t)N_EDGES * 4);
  int*      dst32    = (int*)     alloc((size_t)N_EDGES * 4);
  int2*     csr      = (int2*)    alloc((size_t)TOT * 8);
  __half2*  Wt0      = (__half2*) alloc((size_t)8192 * 4);
  __half2*  Wt1      = (__half2*) alloc((size_t)8192 * 4);
  int*      chunksums= (int*)     alloc(64 * 4);
  float*    scal     = (float*)   alloc(64 * 4);   // [0]=sum(edge_attr) [1]=ce0 [2]=ce1
  int*      flag     = (int*)     alloc(64);

  hipMemsetAsync(deg, 0, (size_t)N_NODES * 4, stream);

  const int EB = (TOT + 255) / 256;
  const int nchunks = (N_NODES + 1023) / 1024;
  const int NB = (N_NODES + 255) / 256;

  prep_kernel<<<1, 128, 0, stream>>>(ei, flag, We0, ae0, We1, ae1, scal);
  wconv_kernel<<<64, 256, 0, stream>>>(W0, W1, Wt0, Wt1);
  mean_kernel<<<256, 256, 0, stream>>>(eatt, scal);
  degconv_kernel<<<EB, 256, 0, stream>>>(ei, flag, deg, src32, dst32);
  scan_chunk_kernel<<<nchunks, 256, 0, stream>>>(deg, rowstart, chunksums);
  scan_top_kernel<<<1, 64, 0, stream>>>(chunksums, nchunks);
  add_off_kernel<<<nchunks, 256, 0, stream>>>(rowstart, rowcur, chunksums);
  fill_kernel<<<EB, 256, 0, stream>>>(src32, dst32, rowcur, csr);

  const int GB = (N_NODES + BM - 1) / BM;   // 782
  const int AB = (N_NODES + 7) / 8;         // agg blocks (8 nodes per block)

  // layer 0 (gemm also streams x into out[:,0:128])
  gemm_kernel<float><<<GB, 128, 0, stream>>>(x, Wt0, hp_h, as0, ad0, ssrc, sdst, out);
  attn_kernel<<<NB, 256, 0, stream>>>(rowstart, csr, eatt, ssrc, sdst, scal, 0, wp, pinv);
  agg_kernel<<<AB, 256, 0, stream>>>(rowstart, csr, wp, pinv, hp_h, b0, h1, out, 128);

  // layer 1
  gemm_kernel<__half><<<GB, 128, 0, stream>>>(h1, Wt1, hp_h, as1, ad1, ssrc, sdst, nullptr);
  attn_kernel<<<NB, 256, 0, stream>>>(rowstart, csr, eatt, ssrc, sdst, scal, 1, wp, pinv);
  agg_kernel<<<AB, 256, 0, stream>>>(rowstart, csr, wp, pinv, hp_h, b1, nullptr, out, 256);
}

// Round 8
// 365.251 us; speedup vs baseline: 2.2678x; 1.0264x over previous
//
#include <hip/hip_runtime.h>
#include <hip/hip_fp16.h>
#include <math.h>

#define N_NODES 50000
#define N_EDGES 600000
#define TOT (N_EDGES + N_NODES)   // 650000 edges incl. self-loops
#define HD 128
#define OUTW 384
#define NEG_SLOPE 0.2f

// ---------- helpers ----------

typedef _Float16 h2_t __attribute__((ext_vector_type(2)));

static __device__ __forceinline__ float fdot2f(h2_t a, h2_t b, float c){
#if __has_builtin(__builtin_amdgcn_fdot2)
  return __builtin_amdgcn_fdot2(a, b, c, false);
#else
  return fmaf((float)a[0], (float)b[0], fmaf((float)a[1], (float)b[1], c));
#endif
}

// edge_index may arrive as int32 or int64; runtime-detected flag (uniform branch)
static __device__ __forceinline__ int load_edge(const void* ei, int is64, long long off){
  return is64 ? (int)((const long long*)ei)[off] : ((const int*)ei)[off];
}

// ---------- one-time per-launch kernels ----------

// fused: int64-layout detect + ce0/ce1 = dot(We, att_e) + scal[0] zero-init
__global__ __launch_bounds__(128) void prep_kernel(const void* ei, int* flag,
                                                   const float* __restrict__ We0, const float* __restrict__ ae0,
                                                   const float* __restrict__ We1, const float* __restrict__ ae1,
                                                   float* scal){
  __shared__ float buf[128];
  __shared__ int okbuf;
  int t = threadIdx.x;
  if (t == 0) okbuf = 1;
  __syncthreads();
  if (t < 64){
    long long v = ((const long long*)ei)[t];
    if (v < 0 || v >= N_NODES) atomicAnd(&okbuf, 0);
  }
  buf[t] = We0[t] * ae0[t];
  __syncthreads();
  for (int off = 64; off > 0; off >>= 1){ if (t < off) buf[t] += buf[t + off]; __syncthreads(); }
  if (t == 0) scal[1] = buf[0];
  __syncthreads();
  buf[t] = We1[t] * ae1[t];
  __syncthreads();
  for (int off = 64; off > 0; off >>= 1){ if (t < off) buf[t] += buf[t + off]; __syncthreads(); }
  if (t == 0){ scal[2] = buf[0]; scal[0] = 0.f; *flag = okbuf; }
}

// convert both weight matrices to k-paired fp16 layout: Wt[k2*128 + n] = (W[n][2k2], W[n][2k2+1])
__global__ __launch_bounds__(256) void wconv_kernel(const float* __restrict__ W0, const float* __restrict__ W1,
                                                    __half2* __restrict__ Wt0, __half2* __restrict__ Wt1){
  int e = blockIdx.x * 256 + threadIdx.x;     // 0..16383
  if (e >= 16384) return;
  const float* W = (e < 8192) ? W0 : W1;
  __half2* Wt = (e < 8192) ? Wt0 : Wt1;
  int i = e & 8191;
  int n = i & 127, k2 = i >> 7;
  float a = W[n * HD + 2 * k2];
  float b = W[n * HD + 2 * k2 + 1];
  Wt[k2 * 128 + n] = __floats2half2_rn(a, b);
}

// x -> fp16 copy (gemm0 input) + stream x into out[:,0:128] (JK-cat slot 0)
__global__ __launch_bounds__(256) void xconv_kernel(const float* __restrict__ x,
                                                    __half* __restrict__ x16,
                                                    float* __restrict__ out){
  int idx = blockIdx.x * 256 + threadIdx.x;   // one float4 per thread
  if (idx >= N_NODES * HD / 4) return;
  int n = idx >> 5, c4 = idx & 31;
  float4 v = ((const float4*)x)[idx];
  *(float4*)&out[(size_t)n * OUTW + c4 * 4] = v;
  float2 pk;
  ((__half2*)&pk)[0] = __floats2half2_rn(v.x, v.y);
  ((__half2*)&pk)[1] = __floats2half2_rn(v.z, v.w);
  *(float2*)&x16[(size_t)idx * 4] = pk;
}

__global__ __launch_bounds__(256) void mean_kernel(const float* __restrict__ ea, float* meansum){
  int tid = blockIdx.x * blockDim.x + threadIdx.x;
  float s = 0.f;
  for (int i = tid; i < N_EDGES; i += gridDim.x * blockDim.x) s += ea[i];
  for (int off = 32; off > 0; off >>= 1) s += __shfl_down(s, off, 64);
  __shared__ float ws[4];
  int lane = threadIdx.x & 63, w = threadIdx.x >> 6;
  if (lane == 0) ws[w] = s;
  __syncthreads();
  if (threadIdx.x == 0){
    atomicAdd(meansum, ws[0] + ws[1] + ws[2] + ws[3]);
  }
}

// degree count + one-time int64 -> int32 src/dst decode (coalesced write)
__global__ __launch_bounds__(256) void degconv_kernel(const void* ei, const int* flag, int* deg,
                                                      int* __restrict__ src32, int* __restrict__ dst32){
  int e = blockIdx.x * 256 + threadIdx.x;
  if (e >= TOT) return;
  int is64 = *flag;
  int d;
  if (e < N_EDGES){
    int s = load_edge(ei, is64, e);
    d = load_edge(ei, is64, (long long)N_EDGES + e);
    src32[e] = s;
    dst32[e] = d;
  } else {
    d = e - N_EDGES;
  }
  atomicAdd(&deg[d], 1);
}

// exclusive scan of deg[0..N) -> rowstart, 1024-element chunks
__global__ __launch_bounds__(256) void scan_chunk_kernel(const int* __restrict__ deg,
                                                         int* __restrict__ rowstart,
                                                         int* __restrict__ chunksums){
  __shared__ int sums[256];
  int t = threadIdx.x;
  int base = blockIdx.x * 1024 + t * 4;
  int v[4];
  #pragma unroll
  for (int i = 0; i < 4; i++) v[i] = (base + i < N_NODES) ? deg[base + i] : 0;
  int tsum = v[0] + v[1] + v[2] + v[3];
  sums[t] = tsum;
  __syncthreads();
  for (int off = 1; off < 256; off <<= 1){
    int add = (t >= off) ? sums[t - off] : 0;
    __syncthreads();
    sums[t] += add;
    __syncthreads();
  }
  int run = sums[t] - tsum;
  #pragma unroll
  for (int i = 0; i < 4; i++){
    if (base + i < N_NODES) rowstart[base + i] = run;
    run += v[i];
  }
  if (t == 255) chunksums[blockIdx.x] = sums[255];
}

__global__ void scan_top_kernel(int* chunksums, int nchunks){
  if (threadIdx.x == 0 && blockIdx.x == 0){
    int run = 0;
    for (int c = 0; c < nchunks; c++){ int v = chunksums[c]; chunksums[c] = run; run += v; }
  }
}

// add chunk offsets; also emit a second copy (rowcur) used as the fill cursor
__global__ __launch_bounds__(256) void add_off_kernel(int* rowstart, int* rowcur, const int* chunksums){
  int base = blockIdx.x * 1024 + threadIdx.x * 4;
  int off = chunksums[blockIdx.x];
  #pragma unroll
  for (int i = 0; i < 4; i++){
    if (base + i < N_NODES){
      int v = rowstart[base + i] + off;
      rowstart[base + i] = v;
      rowcur[base + i] = v;
    }
  }
}

// bucket fill: one packed int2 (src, eid) scattered store per edge
__global__ __launch_bounds__(256) void fill_kernel(const int* __restrict__ src32,
                                                   const int* __restrict__ dst32,
                                                   int* rowcur, int2* __restrict__ csr){
  int e = blockIdx.x * 256 + threadIdx.x;
  if (e >= TOT) return;
  int s, d;
  if (e < N_EDGES){
    s = src32[e];
    d = dst32[e];
  } else {
    s = d = e - N_EDGES;
  }
  int pos = atomicAdd(&rowcur[d], 1);
  csr[pos] = make_int2(s, e);
}

// ---------- per-layer kernels ----------

// fdot2 GEMM: hp_h[M,128] = fp16( hin[M,128] @ W^T ), fp16 input, W pre-packed fp16 [k2][n].
// BM=128 rows/block, 256 threads (4 waves), 8 rows x 8 cols per thread.
// LDS exactly 64 KB: A [k2][m] 32 KB + W [k2][n] 32 KB; ONE barrier; 2 blocks/CU (8 waves).
// Inner reads conflict-free (A: 4x b128 16-lane broadcast; W: 2-way). Staging writes are
// 16-way conflicted (~1 us/dispatch) -- accepted, latency is the real constraint.
// Fused epilogue: ssrc/sdst row dots.
#define BM 128

__global__ __launch_bounds__(256, 2) void gemm_kernel(const __half* __restrict__ hin,
                                                      const __half2* __restrict__ Wt,
                                                      __half* __restrict__ hp_h,
                                                      const float* __restrict__ as_,
                                                      const float* __restrict__ ad_,
                                                      float* __restrict__ ssrc,
                                                      float* __restrict__ sdst){
  __shared__ __half2 As2[64 * 128];    // [k2][m] 32768 B
  __shared__ __half2 Wh2[64 * 128];    // [k2][n] 32768 B
  int t  = threadIdx.x;
  int tx = t & 15;
  int ty = t >> 4;                     // 0..15 -> rows ty*8..+7
  int rb = blockIdx.x * BM;

  // stage W: straight 32KB copy (coalesced, conflict-free)
  {
    const float4* src = (const float4*)Wt;
    float4* dst = (float4*)Wh2;
    #pragma unroll
    for (int p = 0; p < 8; p++) dst[t + p * 256] = src[t + p * 256];
  }
  // stage A: 128 rows x 128 halves, packed to [k2][m]
  #pragma unroll
  for (int p = 0; p < 8; p++){
    int idx = t + p * 256;             // 0..2047 float4s (8 halves each)
    int row = idx >> 4, c8 = idx & 15;
    int gr = rb + row; if (gr >= N_NODES) gr = N_NODES - 1;
    float4 v = *(const float4*)&hin[(size_t)gr * HD + c8 * 8];
    __half2* hv = (__half2*)&v;
    #pragma unroll
    for (int q = 0; q < 4; q++) As2[(4 * c8 + q) * 128 + row] = hv[q];
  }
  __syncthreads();

  float acc[8][8];
  #pragma unroll
  for (int i = 0; i < 8; i++)
    #pragma unroll
    for (int j = 0; j < 8; j++) acc[i][j] = 0.f;

  #pragma unroll 4
  for (int k2 = 0; k2 < 64; k2++){
    float4 ar0 = *(const float4*)&As2[k2 * 128 + ty * 8];        // m = ty*8..+3
    float4 ar1 = *(const float4*)&As2[k2 * 128 + ty * 8 + 4];    // m = +4..+7
    float4 wr0 = *(const float4*)&Wh2[k2 * 128 + tx * 4];        // n = tx*4..+3
    float4 wr1 = *(const float4*)&Wh2[k2 * 128 + 64 + tx * 4];   // n = 64+tx*4..+3
    const h2_t* av0 = (const h2_t*)&ar0;
    const h2_t* av1 = (const h2_t*)&ar1;
    const h2_t* wv0 = (const h2_t*)&wr0;
    const h2_t* wv1 = (const h2_t*)&wr1;
    #pragma unroll
    for (int i = 0; i < 8; i++){
      h2_t ai = (i < 4) ? av0[i] : av1[i - 4];
      #pragma unroll
      for (int j = 0; j < 4; j++){
        acc[i][j]     = fdot2f(ai, wv0[j], acc[i][j]);
        acc[i][j + 4] = fdot2f(ai, wv1[j], acc[i][j + 4]);
      }
    }
  }

  // store hp (fp16): two 8B chunks per row (cols tx*4 and 64+tx*4)
  #pragma unroll
  for (int i = 0; i < 8; i++){
    int r = rb + ty * 8 + i;
    if (r < N_NODES){
      float2 s0, s1;
      ((__half2*)&s0)[0] = __floats2half2_rn(acc[i][0], acc[i][1]);
      ((__half2*)&s0)[1] = __floats2half2_rn(acc[i][2], acc[i][3]);
      ((__half2*)&s1)[0] = __floats2half2_rn(acc[i][4], acc[i][5]);
      ((__half2*)&s1)[1] = __floats2half2_rn(acc[i][6], acc[i][7]);
      *(float2*)&hp_h[(size_t)r * HD + tx * 4]      = s0;
      *(float2*)&hp_h[(size_t)r * HD + 64 + tx * 4] = s1;
    }
  }

  // fused score: per-row dot with att_src/att_dst, reduce over the 16 col-groups
  float as_v[8], ad_v[8];
  #pragma unroll
  for (int j = 0; j < 4; j++){
    as_v[j]     = as_[tx * 4 + j];      ad_v[j]     = ad_[tx * 4 + j];
    as_v[j + 4] = as_[64 + tx * 4 + j]; ad_v[j + 4] = ad_[64 + tx * 4 + j];
  }
  #pragma unroll
  for (int i = 0; i < 8; i++){
    float ps = 0.f, pd = 0.f;
    #pragma unroll
    for (int j = 0; j < 8; j++){
      ps = fmaf(acc[i][j], as_v[j], ps);
      pd = fmaf(acc[i][j], ad_v[j], pd);
    }
    #pragma unroll
    for (int off = 8; off > 0; off >>= 1){
      ps += __shfl_down(ps, off, 16);
      pd += __shfl_down(pd, off, 16);
    }
    int r = rb + ty * 8 + i;
    if (tx == 0 && r < N_NODES){ ssrc[r] = ps; sdst[r] = pd; }
  }
}

// node-parallel attention: 1 thread per dst node; computes exp-weights in CSR
// order (wp[i], coalesced for agg) and the per-node 1/denominator (no atomics).
__global__ __launch_bounds__(256) void attn_kernel(const int* __restrict__ rowstart,
                                                   const int2* __restrict__ csr,
                                                   const float* __restrict__ eattr,
                                                   const float* __restrict__ ssrc,
                                                   const float* __restrict__ sdst,
                                                   const float* __restrict__ scal, int which,
                                                   float* __restrict__ wp,
                                                   float* __restrict__ pinv){
  int n = blockIdx.x * 256 + threadIdx.x;
  if (n >= N_NODES) return;
  int s0 = rowstart[n];
  int s1 = (n + 1 < N_NODES) ? rowstart[n + 1] : TOT;
  float sd = sdst[n];
  float ce = scal[1 + which];
  float mean_ea = scal[0] * (1.0f / (float)N_EDGES);
  float sum = 0.f;
  for (int i = s0; i < s1; i++){
    int2 se = csr[i];
    float eav = (se.y < N_EDGES) ? eattr[se.y] : mean_ea;
    float a = ssrc[se.x] + sd + eav * ce;
    a = (a >= 0.f) ? a : NEG_SLOPE * a;   // leaky_relu
    float w = expf(a);
    wp[i] = w;
    sum += w;
  }
  pinv[n] = 1.0f / (sum + 1e-16f);
}

// aggregation: 32 lanes per dst node (2 nodes per wave, 8 per 256-block),
// lane covers 4 cols (half4 = 8B), edge loop unrolled x4; weights read
// sequentially (broadcast), 1/denom folded into the epilogue.
__global__ __launch_bounds__(256) void agg_kernel(const int* __restrict__ rowstart,
                                                  const int2* __restrict__ csr,
                                                  const float* __restrict__ wp,
                                                  const float* __restrict__ pinv,
                                                  const __half* __restrict__ hp_h,
                                                  const float* __restrict__ bias,
                                                  __half* __restrict__ hnext,
                                                  float* __restrict__ out, int outoff){
  int sub  = threadIdx.x >> 5;     // 0..7 : node slot within block
  int lane = threadIdx.x & 31;     // covers cols 4*lane .. +3
  int n = blockIdx.x * 8 + sub;
  if (n >= N_NODES) return;
  int s0 = rowstart[n];
  int s1 = (n + 1 < N_NODES) ? rowstart[n + 1] : TOT;
  const float2* hb = (const float2*)hp_h;   // one float2 = 4 halves; row stride = 32

  float a0 = 0.f, a1 = 0.f, a2 = 0.f, a3 = 0.f;
  int i = s0;
  for (; i + 4 <= s1; i += 4){
    int2 se0 = csr[i],     se1 = csr[i + 1];
    int2 se2 = csr[i + 2], se3 = csr[i + 3];
    float p0 = wp[i],     p1 = wp[i + 1];
    float p2 = wp[i + 2], p3 = wp[i + 3];
    float2 r0 = hb[(size_t)se0.x * 32 + lane];
    float2 r1 = hb[(size_t)se1.x * 32 + lane];
    float2 r2 = hb[(size_t)se2.x * 32 + lane];
    float2 r3 = hb[(size_t)se3.x * 32 + lane];
    float2 f;
    f = __half22float2(*(__half2*)&r0.x); a0 = fmaf(p0, f.x, a0); a1 = fmaf(p0, f.y, a1);
    f = __half22float2(*(__half2*)&r0.y); a2 = fmaf(p0, f.x, a2); a3 = fmaf(p0, f.y, a3);
    f = __half22float2(*(__half2*)&r1.x); a0 = fmaf(p1, f.x, a0); a1 = fmaf(p1, f.y, a1);
    f = __half22float2(*(__half2*)&r1.y); a2 = fmaf(p1, f.x, a2); a3 = fmaf(p1, f.y, a3);
    f = __half22float2(*(__half2*)&r2.x); a0 = fmaf(p2, f.x, a0); a1 = fmaf(p2, f.y, a1);
    f = __half22float2(*(__half2*)&r2.y); a2 = fmaf(p2, f.x, a2); a3 = fmaf(p2, f.y, a3);
    f = __half22float2(*(__half2*)&r3.x); a0 = fmaf(p3, f.x, a0); a1 = fmaf(p3, f.y, a1);
    f = __half22float2(*(__half2*)&r3.y); a2 = fmaf(p3, f.x, a2); a3 = fmaf(p3, f.y, a3);
  }
  for (; i < s1; i++){
    int2 se = csr[i];
    float p = wp[i];
    float2 r = hb[(size_t)se.x * 32 + lane];
    float2 f;
    f = __half22float2(*(__half2*)&r.x); a0 = fmaf(p, f.x, a0); a1 = fmaf(p, f.y, a1);
    f = __half22float2(*(__half2*)&r.y); a2 = fmaf(p, f.x, a2); a3 = fmaf(p, f.y, a3);
  }

  float inv = pinv[n];
  float4 b4 = *(const float4*)&bias[lane * 4];
  float v0 = fmaf(a0, inv, b4.x); v0 = v0 > 0.f ? v0 : 0.f;
  float v1 = fmaf(a1, inv, b4.y); v1 = v1 > 0.f ? v1 : 0.f;
  float v2 = fmaf(a2, inv, b4.z); v2 = v2 > 0.f ? v2 : 0.f;
  float v3 = fmaf(a3, inv, b4.w); v3 = v3 > 0.f ? v3 : 0.f;
  if (hnext){
    float2 pk;
    __half2* p2h = (__half2*)&pk;
    p2h[0] = __floats2half2_rn(v0, v1);
    p2h[1] = __floats2half2_rn(v2, v3);
    *(float2*)&hnext[(size_t)n * HD + lane * 4] = pk;
  }
  *(float4*)&out[(size_t)n * OUTW + outoff + lane * 4] = make_float4(v0, v1, v2, v3);
}

// ---------- launch ----------

extern "C" void kernel_launch(void* const* d_in, const int* in_sizes, int n_in,
                              void* d_out, int out_size, void* d_ws, size_t ws_size,
                              hipStream_t stream){
  (void)in_sizes; (void)n_in; (void)out_size; (void)ws_size;
  const float* x    = (const float*)d_in[0];
  const void*  ei   = d_in[1];
  const float* eatt = (const float*)d_in[2];
  const float* W0   = (const float*)d_in[3];
  const float* as0  = (const float*)d_in[4];
  const float* ad0  = (const float*)d_in[5];
  const float* We0  = (const float*)d_in[6];
  const float* ae0  = (const float*)d_in[7];
  const float* b0   = (const float*)d_in[8];
  const float* W1   = (const float*)d_in[9];
  const float* as1  = (const float*)d_in[10];
  const float* ad1  = (const float*)d_in[11];
  const float* We1  = (const float*)d_in[12];
  const float* ae1  = (const float*)d_in[13];
  const float* b1   = (const float*)d_in[14];
  float* out = (float*)d_out;

  char* ws = (char*)d_ws;
  size_t off = 0;
  auto alloc = [&](size_t bytes) -> void* {
    void* p = ws + off;
    off += (bytes + 255) & ~(size_t)255;
    return p;
  };
  __half*   hp_h     = (__half*)  alloc((size_t)N_NODES * HD * 2);
  __half*   h1       = (__half*)  alloc((size_t)N_NODES * HD * 2);
  __half*   x16      = (__half*)  alloc((size_t)N_NODES * HD * 2);
  float*    ssrc     = (float*)   alloc((size_t)N_NODES * 4);
  float*    sdst     = (float*)   alloc((size_t)N_NODES * 4);
  float*    wp       = (float*)   alloc((size_t)TOT * 4);
  float*    pinv     = (float*)   alloc((size_t)N_NODES * 4);
  int*      deg      = (int*)     alloc((size_t)N_NODES * 4);
  int*      rowstart = (int*)     alloc((size_t)N_NODES * 4);
  int*      rowcur   = (int*)     alloc((size_t)N_NODES * 4);
  int*      src32    = (int*)     alloc((size_t)N_EDGES * 4);
  int*      dst32    = (int*)     alloc((size_t)N_EDGES * 4);
  int2*     csr      = (int2*)    alloc((size_t)TOT * 8);
  __half2*  Wt0      = (__half2*) alloc((size_t)8192 * 4);
  __half2*  Wt1      = (__half2*) alloc((size_t)8192 * 4);
  int*      chunksums= (int*)     alloc(64 * 4);
  float*    scal     = (float*)   alloc(64 * 4);   // [0]=sum(edge_attr) [1]=ce0 [2]=ce1
  int*      flag     = (int*)     alloc(64);

  hipMemsetAsync(deg, 0, (size_t)N_NODES * 4, stream);

  const int EB = (TOT + 255) / 256;
  const int nchunks = (N_NODES + 1023) / 1024;
  const int NB = (N_NODES + 255) / 256;

  prep_kernel<<<1, 128, 0, stream>>>(ei, flag, We0, ae0, We1, ae1, scal);
  wconv_kernel<<<64, 256, 0, stream>>>(W0, W1, Wt0, Wt1);
  xconv_kernel<<<(N_NODES * HD / 4 + 255) / 256, 256, 0, stream>>>(x, x16, out);
  mean_kernel<<<256, 256, 0, stream>>>(eatt, scal);
  degconv_kernel<<<EB, 256, 0, stream>>>(ei, flag, deg, src32, dst32);
  scan_chunk_kernel<<<nchunks, 256, 0, stream>>>(deg, rowstart, chunksums);
  scan_top_kernel<<<1, 64, 0, stream>>>(chunksums, nchunks);
  add_off_kernel<<<nchunks, 256, 0, stream>>>(rowstart, rowcur, chunksums);
  fill_kernel<<<EB, 256, 0, stream>>>(src32, dst32, rowcur, csr);

  const int GB = (N_NODES + BM - 1) / BM;   // 391
  const int AB = (N_NODES + 7) / 8;         // agg blocks (8 nodes per block)

  // layer 0
  gemm_kernel<<<GB, 256, 0, stream>>>(x16, Wt0, hp_h, as0, ad0, ssrc, sdst);
  attn_kernel<<<NB, 256, 0, stream>>>(rowstart, csr, eatt, ssrc, sdst, scal, 0, wp, pinv);
  agg_kernel<<<AB, 256, 0, stream>>>(rowstart, csr, wp, pinv, hp_h, b0, h1, out, 128);

  // layer 1
  gemm_kernel<<<GB, 256, 0, stream>>>(h1, Wt1, hp_h, as1, ad1, ssrc, sdst);
  attn_kernel<<<NB, 256, 0, stream>>>(rowstart, csr, eatt, ssrc, sdst, scal, 1, wp, pinv);
  agg_kernel<<<AB, 256, 0, stream>>>(rowstart, csr, wp, pinv, hp_h, b1, nullptr, out, 256);
}